// Round 1
// 876.728 us; speedup vs baseline: 1.2411x; 1.2411x over previous
//
#include <hip/hip_runtime.h>
#include <hip/hip_bf16.h>
#include <math.h>

#define E_DIM 1024
#define NHEAD 16
#define HID_DIM 2730
#define KP_FC2 2752            // fc2 K padded (zero weight rows) -> mult of 64
#define HB_LD 5504             // hbuf row stride (16B-aligned)
#define B_DIM 8
#define S_DIM 1025
#define EPS_V 1e-6f
#define SCALE_V 0.125f
#define MROWS (B_DIM * S_DIM)   // 8200

typedef __attribute__((ext_vector_type(8))) short short8;
typedef __attribute__((ext_vector_type(4))) float f32x4;
typedef unsigned short us;

__device__ __forceinline__ float b2f(us u) {
    union { unsigned int i; float f; } x; x.i = ((unsigned int)u) << 16; return x.f;
}
__device__ __forceinline__ us f2b(float f) {
    __hip_bfloat16 h = __float2bfloat16(f);
    return *reinterpret_cast<us*>(&h);
}

__device__ __forceinline__ void stage16(const void* g, void* l) {
    __builtin_amdgcn_global_load_lds(
        (const __attribute__((address_space(1))) unsigned int*)g,
        (__attribute__((address_space(3))) unsigned int*)l,
        16, 0, 0);
}

// u16 index of the 8-element group at (row, c8) in a XOR-swizzled [R][64] bf16 tile
__device__ __forceinline__ int sl(int row, int c8) {
    return (row * 8 + (c8 ^ (row & 7))) * 8;
}

#define MFMA16(a, b, c) __builtin_amdgcn_mfma_f32_16x16x32_bf16(a, b, c, 0, 0, 0)

// ---------------- RMSNorm (fp32 in -> bf16 out) ----------------
__global__ __launch_bounds__(256) void rmsnorm_kernel(const float* __restrict__ x,
        const float* __restrict__ g, us* __restrict__ out) {
    int row = blockIdx.x;
    const float4* xr = (const float4*)(x + (size_t)row * E_DIM);
    float4 v = xr[threadIdx.x];
    float ss = v.x*v.x + v.y*v.y + v.z*v.z + v.w*v.w;
    #pragma unroll
    for (int off = 32; off > 0; off >>= 1) ss += __shfl_down(ss, off, 64);
    __shared__ float wsum[4];
    int lane = threadIdx.x & 63, w = threadIdx.x >> 6;
    if (lane == 0) wsum[w] = ss;
    __syncthreads();
    float tot = wsum[0] + wsum[1] + wsum[2] + wsum[3];
    float inv = rsqrtf(tot * (1.0f / E_DIM) + EPS_V);
    float4 gv = ((const float4*)g)[threadIdx.x];
    ushort4 o;
    o.x = f2b(v.x * inv * gv.x); o.y = f2b(v.y * inv * gv.y);
    o.z = f2b(v.z * inv * gv.z); o.w = f2b(v.w * inv * gv.w);
    ((ushort4*)(out + (size_t)row * E_DIM))[threadIdx.x] = o;
}

// ---------------- weight convert+transpose: W[K][N] f32 -> WT[n][k] bf16 ----------------
__global__ __launch_bounds__(256) void convt_kernel(const float* __restrict__ W,
        us* __restrict__ WT, int K, int N, int KPad, int swap_half) {
    __shared__ float T[32][33];
    int n0 = blockIdx.x * 32, k0 = blockIdx.y * 32;
    int c = threadIdx.x & 31, r4 = (threadIdx.x >> 5) << 2;
    #pragma unroll
    for (int i = 0; i < 4; i++) {
        int k = k0 + r4 + i, n = n0 + c;
        int src = n;
        if (swap_half && n < N) src = (n < swap_half) ? n + swap_half : n - swap_half;
        T[c][r4 + i] = (k < K && n < N) ? W[(size_t)k * N + src] : 0.0f;
    }
    __syncthreads();
    #pragma unroll
    for (int i = 0; i < 4; i++) {
        int n = n0 + r4 + i, k = k0 + c;
        if (n < N && k < KPad) WT[(size_t)n * KPad + k] = f2b(T[r4 + i][c]);
    }
}

// ---------------- fc1 bias permute ----------------
__global__ __launch_bounds__(256) void bias_perm_kernel(const float* __restrict__ b,
        float* __restrict__ bp) {
    int r = blockIdx.x * 256 + threadIdx.x;
    if (r < 2 * HID_DIM) bp[r] = b[r < HID_DIM ? r + HID_DIM : r - HID_DIM];
}

// ---------------- 256x256 8-wave MFMA GEMM, 4-phase counted-vmcnt schedule ----------------
// A: [M][lda] bf16, Bt: [N][ldb] bf16 (ldb >= K), K % 64 == 0.
// LDS: 2 buffers x {A-half0, A-half1, B-half0, B-half1} x 128x64 bf16 (16 KiB each) = 128 KiB.
// XOR-swizzle on both the staged global source and the ds_read (rule 21 both-sides).
// Per K-tile: 4 phases, each {ds_read frag subtile | 1 half-tile global_load_lds |
//   s_barrier | setprio(1) 16xMFMA setprio(0) | s_barrier}; vmcnt(4) only at phase 4.
template<bool BF16OUT>
__global__ __launch_bounds__(512, 2) void gemm256(const us* __restrict__ A, int lda,
        const us* __restrict__ Bt, int ldb, const float* __restrict__ bias,
        const float* __restrict__ Rres, void* __restrict__ Cv,
        int M, int N, int K, int ldc) {
    __shared__ __align__(16) us lds[2][4][8192];
    us* const L = &lds[0][0][0];
    const int tid = threadIdx.x;
    const int lane = tid & 63;
    const int w = tid >> 6;
    const int wm = w >> 2, wn = w & 3;           // 2 x 4 wave grid, wave tile 128x64
    const int l15 = lane & 15, quad = lane >> 4;
    const int m0 = blockIdx.y * 256, n0 = blockIdx.x * 256;

    // staging source: thread tid covers swizzled slot (row=tid>>3, c8s=tid&7) and +64 rows
    const int r0 = tid >> 3;
    const int c80 = (tid & 7) ^ (r0 & 7);
    const us* const pA = A + (size_t)(m0 + r0) * lda + c80 * 8;
    const us* const pB = Bt + (size_t)(n0 + r0) * ldb + c80 * 8;
    const size_t a64 = (size_t)64 * lda, b64 = (size_t)64 * ldb;
    us* const dst = L + tid * 8;                 // lane-linear LDS dest (wave-uniform base)

#define STG_A(b, h, kt) do { \
    const us* s_ = pA + (size_t)(h) * 2 * a64 + (size_t)(kt) * 64; \
    stage16(s_,       dst + ((b) * 4 + (h)) * 8192); \
    stage16(s_ + a64, dst + ((b) * 4 + (h)) * 8192 + 4096); \
} while (0)
#define STG_B(b, h, kt) do { \
    const us* s_ = pB + (size_t)(h) * 2 * b64 + (size_t)(kt) * 64; \
    stage16(s_,       dst + ((b) * 4 + 2 + (h)) * 8192); \
    stage16(s_ + b64, dst + ((b) * 4 + 2 + (h)) * 8192 + 4096); \
} while (0)

    f32x4 acc[8][4];
    #pragma unroll
    for (int m = 0; m < 8; m++)
        #pragma unroll
        for (int n = 0; n < 4; n++) acc[m][n] = (f32x4){0.f, 0.f, 0.f, 0.f};

    const int nk = K >> 6;

    // prologue: tile0 (all 4 halves) -> buf0; tile1 B halves -> buf1
    STG_A(0, 0, 0); STG_A(0, 1, 0);
    STG_B(0, 0, 0); STG_B(0, 1, 0);
    STG_B(1, 0, 1); STG_B(1, 1, 1);
    asm volatile("s_waitcnt vmcnt(4)" ::: "memory");   // tile0's 8 loads landed
    __builtin_amdgcn_s_barrier();

    const int brow = (wn & 1) * 64;
    for (int t = 0; t < nk; t++) {
        const int c = t & 1, cn = c ^ 1;
        const us* aB = L + (c * 4 + wm) * 8192;
        const us* bB = L + (c * 4 + 2 + (wn >> 1)) * 8192;
        // B fragments for the whole K-tile (read once, held in regs; frees B regions after ph1)
        short8 bf[4][2];
        #pragma unroll
        for (int n = 0; n < 4; n++) {
            bf[n][0] = *(const short8*)(bB + sl(brow + n * 16 + l15, quad));
            bf[n][1] = *(const short8*)(bB + sl(brow + n * 16 + l15, 4 + quad));
        }
        #pragma unroll
        for (int p = 0; p < 4; p++) {
            const int mp = 2 * p;
            short8 a00 = *(const short8*)(aB + sl(mp * 16 + l15, quad));
            short8 a01 = *(const short8*)(aB + sl(mp * 16 + l15, 4 + quad));
            short8 a10 = *(const short8*)(aB + sl(mp * 16 + 16 + l15, quad));
            short8 a11 = *(const short8*)(aB + sl(mp * 16 + 16 + l15, 4 + quad));
            if (p == 0) {
                if (t + 1 < nk) { STG_A(cn, 0, t + 1); STG_A(cn, 1, t + 1); }
            } else if (p == 1) {
                if (t + 2 < nk) STG_B(c, 0, t + 2);
            } else if (p == 2) {
                if (t + 2 < nk) STG_B(c, 1, t + 2);
            }
            __builtin_amdgcn_s_barrier();
            __builtin_amdgcn_s_setprio(1);
            #pragma unroll
            for (int n = 0; n < 4; n++) {
                acc[mp][n]     = MFMA16(a00, bf[n][0], acc[mp][n]);
                acc[mp][n]     = MFMA16(a01, bf[n][1], acc[mp][n]);
                acc[mp + 1][n] = MFMA16(a10, bf[n][0], acc[mp + 1][n]);
                acc[mp + 1][n] = MFMA16(a11, bf[n][1], acc[mp + 1][n]);
            }
            __builtin_amdgcn_s_setprio(0);
            if (p == 3) {
                // counted wait: allow the 2 B half-tiles staged at ph2/ph3 to stay in flight.
                // tail iterations (stages skipped) must drain fully instead.
                if (t + 2 >= nk) { asm volatile("s_waitcnt vmcnt(0)" ::: "memory"); }
                else             { asm volatile("s_waitcnt vmcnt(4)" ::: "memory"); }
            }
            __builtin_amdgcn_s_barrier();
        }
    }

    // epilogue
    #pragma unroll
    for (int m = 0; m < 8; m++) {
        int gm0 = m0 + wm * 128 + m * 16 + quad * 4;
        #pragma unroll
        for (int n = 0; n < 4; n++) {
            int gn = n0 + wn * 64 + n * 16 + l15;
            if (gn >= N) continue;
            float bs = bias[gn];
            #pragma unroll
            for (int r = 0; r < 4; r++) {
                int gm = gm0 + r;
                if (gm >= M) continue;
                float v = acc[m][n][r] + bs;
                if (BF16OUT) {
                    ((us*)Cv)[(size_t)gm * ldc + gn] = f2b(v);
                } else {
                    ((float*)Cv)[(size_t)gm * ldc + gn] = v + Rres[(size_t)gm * ldc + gn];
                }
            }
        }
    }
#undef STG_A
#undef STG_B
}

// ---------------- RoPE (in-place) + q*SCALE ----------------
__global__ __launch_bounds__(256) void rope_kernel(us* __restrict__ qkv) {
    int idx = blockIdx.x * 256 + threadIdx.x;
    int i = idx & 31;
    int h = (idx >> 5) & (NHEAD - 1);
    int rc = idx >> 9;
    int s = rc % S_DIM;
    us* q = qkv + (size_t)rc * 3072 + h * 64;
    us* k = q + 1024;
    if (s == 0) {
        q[i] = f2b(b2f(q[i]) * SCALE_V);
        q[i + 32] = f2b(b2f(q[i + 32]) * SCALE_V);
        return;
    }
    float pos = (float)(s - 1);
    float invf = expf((float)i * (-9.210340371976184f / 32.0f));
    float f = pos * invf;
    float c = cosf(f), sn = sinf(f);
    float q1 = b2f(q[i]), q2 = b2f(q[i + 32]);
    q[i]      = f2b((q1 * c - q2 * sn) * SCALE_V);
    q[i + 32] = f2b((q2 * c + q1 * sn) * SCALE_V);
    float k1 = b2f(k[i]), k2 = b2f(k[i + 32]);
    k[i]      = f2b(k1 * c - k2 * sn);
    k[i + 32] = f2b(k2 * c + k1 * sn);
}

// ---------------- V transpose ----------------
__global__ __launch_bounds__(256) void vtrans_kernel(const us* __restrict__ qkv,
        us* __restrict__ Vt) {
    __shared__ us T[64][65];
    int st = blockIdx.x, h = blockIdx.y, bc = blockIdx.z;
    int tid = threadIdx.x;
    int r = tid & 63, cb = (tid >> 6) * 16;
    const us* src = qkv + (size_t)(bc * S_DIM + st * 64 + r) * 3072 + 2048 + h * 64 + cb;
    #pragma unroll
    for (int i = 0; i < 4; i++) {
        ushort4 v = *(const ushort4*)(src + i * 4);
        T[cb + i*4 + 0][r] = v.x; T[cb + i*4 + 1][r] = v.y;
        T[cb + i*4 + 2][r] = v.z; T[cb + i*4 + 3][r] = v.w;
    }
    __syncthreads();
    int d = tid >> 2, sc = (tid & 3) * 16;
    us* dstp = Vt + ((size_t)((bc * 16 + h) * 64 + d)) * 1088 + st * 64 + sc;
    #pragma unroll
    for (int g = 0; g < 4; g++) {
        ushort4 o;
        int i0 = sc + g * 4;
        o.x = (st*64 + i0 + 0 < S_DIM) ? T[d][i0 + 0] : 0;
        o.y = (st*64 + i0 + 1 < S_DIM) ? T[d][i0 + 1] : 0;
        o.z = (st*64 + i0 + 2 < S_DIM) ? T[d][i0 + 2] : 0;
        o.w = (st*64 + i0 + 3 < S_DIM) ? T[d][i0 + 3] : 0;
        *(ushort4*)(dstp + g * 4) = o;
    }
}

// ---------------- MFMA flash attention ----------------
__global__ __launch_bounds__(256) void attn_kernel(const us* __restrict__ qkv,
        const us* __restrict__ Vt, us* __restrict__ attnb) {
    __shared__ __align__(16) us Qs[4096];
    __shared__ __align__(16) us Ks[4096];
    __shared__ __align__(16) us Vts[4096];
    __shared__ __align__(16) us Ps[4096];
    int qt = blockIdx.x, h = blockIdx.y, bc = blockIdx.z;
    int tid = threadIdx.x;
    int lane = tid & 63, w = tid >> 6;
    int l15 = lane & 15, quad = lane >> 4;

    const us* qg = qkv + (size_t)(bc * S_DIM + qt * 64) * 3072 + h * 64;
    #pragma unroll
    for (int i = 0; i < 2; i++) {
        int slot = i * 256 + tid;
        int row = slot >> 3, c8 = (slot & 7) ^ (row & 7);
        stage16(qg + (size_t)row * 3072 + c8 * 8, Qs + slot * 8);
    }
    const us* kg = qkv + (size_t)(bc * S_DIM) * 3072 + 1024 + h * 64;
    const us* vgp = Vt + (size_t)((bc * 16 + h) * 64) * 1088;

    f32x4 acc_o[4];
    float mr[4], lr[4];
    #pragma unroll
    for (int r = 0; r < 4; r++) { mr[r] = -1e30f; lr[r] = 0.f; }
    #pragma unroll
    for (int j = 0; j < 4; j++) acc_o[j] = (f32x4){0.f, 0.f, 0.f, 0.f};

    for (int kt = 0; kt < 17; kt++) {
        __syncthreads();
        #pragma unroll
        for (int i = 0; i < 2; i++) {
            int slot = i * 256 + tid;
            int row = slot >> 3, c8 = (slot & 7) ^ (row & 7);
            stage16(kg + (size_t)(kt * 64 + row) * 3072 + c8 * 8, Ks + slot * 8);
            stage16(vgp + (size_t)row * 1088 + kt * 64 + c8 * 8, Vts + slot * 8);
        }
        __syncthreads();

        f32x4 accS[4];
        #pragma unroll
        for (int j = 0; j < 4; j++) accS[j] = (f32x4){0.f, 0.f, 0.f, 0.f};
        short8 qa0 = *(const short8*)(Qs + sl(16 * w + l15, quad));
        short8 qa1 = *(const short8*)(Qs + sl(16 * w + l15, 4 + quad));
        #pragma unroll
        for (int j = 0; j < 4; j++) {
            short8 kb0 = *(const short8*)(Ks + sl(16 * j + l15, quad));
            short8 kb1 = *(const short8*)(Ks + sl(16 * j + l15, 4 + quad));
            accS[j] = __builtin_amdgcn_mfma_f32_16x16x32_bf16(qa0, kb0, accS[j], 0, 0, 0);
            accS[j] = __builtin_amdgcn_mfma_f32_16x16x32_bf16(qa1, kb1, accS[j], 0, 0, 0);
        }
        float pr[4][4];
        #pragma unroll
        for (int j = 0; j < 4; j++) {
            if (kt * 64 + 16 * j + l15 >= S_DIM) {
                #pragma unroll
                for (int r = 0; r < 4; r++) accS[j][r] = -1e30f;
            }
        }
        #pragma unroll
        for (int r = 0; r < 4; r++) {
            float tm = fmaxf(fmaxf(accS[0][r], accS[1][r]), fmaxf(accS[2][r], accS[3][r]));
            #pragma unroll
            for (int off = 1; off < 16; off <<= 1)
                tm = fmaxf(tm, __shfl_xor(tm, off, 64));
            float mnew = fmaxf(mr[r], tm);
            float al = __expf(mr[r] - mnew);
            mr[r] = mnew;
            float rs = 0.f;
            #pragma unroll
            for (int j = 0; j < 4; j++) {
                float p = __expf(accS[j][r] - mnew);
                pr[j][r] = p;
                rs += p;
            }
            #pragma unroll
            for (int off = 1; off < 16; off <<= 1)
                rs += __shfl_xor(rs, off, 64);
            lr[r] = lr[r] * al + rs;
            #pragma unroll
            for (int j = 0; j < 4; j++) acc_o[j][r] *= al;
        }
        #pragma unroll
        for (int j = 0; j < 4; j++) {
            #pragma unroll
            for (int r = 0; r < 4; r++) {
                int prow = quad * 4 + r;
                int idx = sl(16 * w + prow, 2 * j + (l15 >> 3)) + (l15 & 7);
                Ps[idx] = f2b(pr[j][r]);
            }
        }
        short8 pa0 = *(const short8*)(Ps + sl(16 * w + l15, quad));
        short8 pa1 = *(const short8*)(Ps + sl(16 * w + l15, 4 + quad));
        #pragma unroll
        for (int j = 0; j < 4; j++) {
            short8 vb0 = *(const short8*)(Vts + sl(16 * j + l15, quad));
            short8 vb1 = *(const short8*)(Vts + sl(16 * j + l15, 4 + quad));
            acc_o[j] = __builtin_amdgcn_mfma_f32_16x16x32_bf16(pa0, vb0, acc_o[j], 0, 0, 0);
            acc_o[j] = __builtin_amdgcn_mfma_f32_16x16x32_bf16(pa1, vb1, acc_o[j], 0, 0, 0);
        }
    }
    #pragma unroll
    for (int r = 0; r < 4; r++) {
        int s = qt * 64 + 16 * w + quad * 4 + r;
        if (s >= S_DIM) continue;
        float invl = 1.0f / lr[r];
        #pragma unroll
        for (int j = 0; j < 4; j++)
            attnb[(size_t)(bc * S_DIM + s) * E_DIM + h * 64 + 16 * j + l15] =
                f2b(acc_o[j][r] * invl);
    }
}

// ---------------- depthwise conv + GELU + gate ----------------
__global__ __launch_bounds__(256) void conv_gelu_kernel(us* __restrict__ hb,
        const float* __restrict__ dw_w, const float* __restrict__ dw_b) {
    int p = blockIdx.x % S_DIM;
    size_t row = blockIdx.x;
    size_t brow = row - p;
    for (int c = threadIdx.x; c < HID_DIM; c += 256) {
        float val;
        if (p == 0) {
            val = b2f(hb[row * HB_LD + HID_DIM + c]);
        } else {
            int pp = p - 1;
            int gy = pp >> 5, gx = pp & 31;
            float a = dw_b[c];
            #pragma unroll
            for (int dy = 0; dy < 3; dy++) {
                int ny = gy + dy - 1;
                if (ny < 0 || ny >= 32) continue;
                #pragma unroll
                for (int dx = 0; dx < 3; dx++) {
                    int nx = gx + dx - 1;
                    if (nx < 0 || nx >= 32) continue;
                    a = fmaf(b2f(hb[(brow + 1 + ny * 32 + nx) * HB_LD + HID_DIM + c]),
                             dw_w[(dy * 3 + dx) * HID_DIM + c], a);
                }
            }
            val = a;
        }
        float ge = 0.5f * val * (1.0f + erff(val * 0.70710678118654752f));
        hb[row * HB_LD + c] = f2b(ge * b2f(hb[row * HB_LD + c]));
    }
}

// ---------------- launch ----------------
static size_t ws_need(int cb) {
    size_t R = (size_t)cb * 1025, Rp = ((R + 127) / 128) * 128;
    size_t end1 = Rp*1024*2 + Rp*3072*2 + (size_t)cb*16*64*1088*2
                + 8320ull*1024*2 + 3072ull*1024*2 + 1024ull*1024*2;
    size_t end2 = Rp*1024*2 + Rp*HB_LD*2 + 5504ull*1024*2 + 1024ull*KP_FC2*2 + 5460*4;
    return end1 > end2 ? end1 : end2;
}

extern "C" void kernel_launch(void* const* d_in, const int* in_sizes, int n_in,
                              void* d_out, int out_size, void* d_ws, size_t ws_size,
                              hipStream_t stream) {
    const float* x      = (const float*)d_in[0];
    const float* g1     = (const float*)d_in[1];
    const float* w_qkv  = (const float*)d_in[2];
    const float* b_qkv  = (const float*)d_in[3];
    const float* w_proj = (const float*)d_in[4];
    const float* b_proj = (const float*)d_in[5];
    const float* g2     = (const float*)d_in[6];
    const float* fc1_w  = (const float*)d_in[7];
    const float* fc1_b  = (const float*)d_in[8];
    const float* dw_w   = (const float*)d_in[9];
    const float* dw_b   = (const float*)d_in[10];
    const float* fc2_w  = (const float*)d_in[11];
    const float* fc2_b  = (const float*)d_in[12];
    float* out = (float*)d_out;
    char* base = (char*)d_ws;

    int CB = 2;
    if (ws_size >= ws_need(8)) CB = 8;
    else if (ws_size >= ws_need(4)) CB = 4;
    int NC = B_DIM / CB;
    size_t R = (size_t)CB * 1025, Rp = ((R + 127) / 128) * 128;
    int gy256 = (int)((R + 255) / 256);

    // phase-1 layout
    us* xn    = (us*)base;                       // Rp x 1024
    size_t o  = Rp * 1024 * 2;
    us* qkv   = (us*)(base + o);                 // Rp x 3072 (phase1)
    us* hbuf  = (us*)(base + o);                 // Rp x HB_LD (phase2 overlay)
    size_t o2 = o + Rp * 3072 * 2;
    us* Vt    = (us*)(base + o2);                // CB x 16 x 64 x 1088
    size_t o3 = o2 + (size_t)CB * 16 * 64 * 1088 * 2;
    us* attnb = (us*)(base + o3);                // 8320 x 1024
    size_t o4 = o3 + 8320ull * 1024 * 2;
    us* qkvT  = (us*)(base + o4);                // 3072 x 1024
    size_t o5 = o4 + 3072ull * 1024 * 2;
    us* projT = (us*)(base + o5);                // 1024 x 1024
    // phase-2 layout (overlays qkv/Vt/attnb/qkvT/projT)
    size_t p2 = o + Rp * HB_LD * 2;
    us* fc1T  = (us*)(base + p2);                // 5504 x 1024
    size_t p3 = p2 + 5504ull * 1024 * 2;
    us* fc2T  = (us*)(base + p3);                // 1024 x KP_FC2
    float* fc1bp = (float*)(base + p3 + 1024ull * KP_FC2 * 2);   // 5460 f32

    // ---- attention phase ----
    convt_kernel<<<dim3(96, 32), 256, 0, stream>>>(w_qkv, qkvT, 1024, 3072, 1024, 0);
    convt_kernel<<<dim3(32, 32), 256, 0, stream>>>(w_proj, projT, 1024, 1024, 1024, 0);
    for (int c = 0; c < NC; c++) {
        size_t roff = (size_t)c * R;
        rmsnorm_kernel<<<(int)R, 256, 0, stream>>>(x + roff * E_DIM, g1, xn);
        gemm256<true><<<dim3(12, gy256), 512, 0, stream>>>(xn, 1024, qkvT, 1024,
                b_qkv, nullptr, qkv, (int)R, 3072, 1024, 3072);
        rope_kernel<<<(int)(2 * R), 256, 0, stream>>>(qkv);
        vtrans_kernel<<<dim3(17, 16, CB), 256, 0, stream>>>(qkv, Vt);
        attn_kernel<<<dim3(17, 16, CB), 256, 0, stream>>>(qkv, Vt, attnb + roff * E_DIM);
    }
    gemm256<false><<<dim3(4, (MROWS + 255) / 256), 512, 0, stream>>>(attnb, 1024,
            projT, 1024, b_proj, x, out, MROWS, 1024, 1024, 1024);

    // ---- MLP phase ----
    convt_kernel<<<dim3(171, 32), 256, 0, stream>>>(fc1_w, fc1T, 1024, 5460, 1024, HID_DIM);
    convt_kernel<<<dim3(32, 86), 256, 0, stream>>>(fc2_w, fc2T, HID_DIM, 1024, KP_FC2, 0);
    bias_perm_kernel<<<22, 256, 0, stream>>>(fc1_b, fc1bp);
    for (int c = 0; c < NC; c++) {
        size_t roff = (size_t)c * R;
        float* outc = out + roff * E_DIM;
        rmsnorm_kernel<<<(int)R, 256, 0, stream>>>(outc, g2, xn);
        gemm256<true><<<dim3(22, gy256), 512, 0, stream>>>(xn, 1024, fc1T, 1024,
                fc1bp, nullptr, hbuf, (int)R, 5460, 1024, HB_LD);
        conv_gelu_kernel<<<(int)R, 256, 0, stream>>>(hbuf, dw_w, dw_b);
        gemm256<false><<<dim3(4, gy256), 512, 0, stream>>>(hbuf, HB_LD, fc2T, KP_FC2,
                fc2_b, outc, outc, (int)R, 1024, KP_FC2, 1024);
    }
}

// Round 2
// 841.221 us; speedup vs baseline: 1.2935x; 1.0422x over previous
//
#include <hip/hip_runtime.h>
#include <hip/hip_bf16.h>
#include <math.h>

#define E_DIM 1024
#define NHEAD 16
#define HID_DIM 2730
#define KP_FC2 2752            // fc2 K padded (zero weight rows) -> mult of 64
#define HB_LD 5504             // hbuf row stride (16B-aligned)
#define B_DIM 8
#define S_DIM 1025
#define EPS_V 1e-6f
#define SCALE_V 0.125f
#define MROWS (B_DIM * S_DIM)   // 8200

typedef __attribute__((ext_vector_type(8))) short short8;
typedef __attribute__((ext_vector_type(4))) float f32x4;
typedef unsigned short us;

__device__ __forceinline__ float b2f(us u) {
    union { unsigned int i; float f; } x; x.i = ((unsigned int)u) << 16; return x.f;
}
__device__ __forceinline__ us f2b(float f) {
    __hip_bfloat16 h = __float2bfloat16(f);
    return *reinterpret_cast<us*>(&h);
}

__device__ __forceinline__ void stage16(const void* g, void* l) {
    __builtin_amdgcn_global_load_lds(
        (const __attribute__((address_space(1))) unsigned int*)g,
        (__attribute__((address_space(3))) unsigned int*)l,
        16, 0, 0);
}

// u16 index of the 8-element group at (row, c8) in a XOR-swizzled [R][64] bf16 tile
__device__ __forceinline__ int sl(int row, int c8) {
    return (row * 8 + (c8 ^ (row & 7))) * 8;
}

#define MFMA16(a, b, c) __builtin_amdgcn_mfma_f32_16x16x32_bf16(a, b, c, 0, 0, 0)

// ---------------- RMSNorm (fp32 in -> bf16 out) ----------------
__global__ __launch_bounds__(256) void rmsnorm_kernel(const float* __restrict__ x,
        const float* __restrict__ g, us* __restrict__ out) {
    int row = blockIdx.x;
    const float4* xr = (const float4*)(x + (size_t)row * E_DIM);
    float4 v = xr[threadIdx.x];
    float ss = v.x*v.x + v.y*v.y + v.z*v.z + v.w*v.w;
    #pragma unroll
    for (int off = 32; off > 0; off >>= 1) ss += __shfl_down(ss, off, 64);
    __shared__ float wsum[4];
    int lane = threadIdx.x & 63, w = threadIdx.x >> 6;
    if (lane == 0) wsum[w] = ss;
    __syncthreads();
    float tot = wsum[0] + wsum[1] + wsum[2] + wsum[3];
    float inv = rsqrtf(tot * (1.0f / E_DIM) + EPS_V);
    float4 gv = ((const float4*)g)[threadIdx.x];
    ushort4 o;
    o.x = f2b(v.x * inv * gv.x); o.y = f2b(v.y * inv * gv.y);
    o.z = f2b(v.z * inv * gv.z); o.w = f2b(v.w * inv * gv.w);
    ((ushort4*)(out + (size_t)row * E_DIM))[threadIdx.x] = o;
}

// ---------------- weight convert+transpose: W[K][N] f32 -> WT[n][k] bf16 ----------------
__global__ __launch_bounds__(256) void convt_kernel(const float* __restrict__ W,
        us* __restrict__ WT, int K, int N, int KPad, int swap_half) {
    __shared__ float T[32][33];
    int n0 = blockIdx.x * 32, k0 = blockIdx.y * 32;
    int c = threadIdx.x & 31, r4 = (threadIdx.x >> 5) << 2;
    #pragma unroll
    for (int i = 0; i < 4; i++) {
        int k = k0 + r4 + i, n = n0 + c;
        int src = n;
        if (swap_half && n < N) src = (n < swap_half) ? n + swap_half : n - swap_half;
        T[c][r4 + i] = (k < K && n < N) ? W[(size_t)k * N + src] : 0.0f;
    }
    __syncthreads();
    #pragma unroll
    for (int i = 0; i < 4; i++) {
        int n = n0 + r4 + i, k = k0 + c;
        if (n < N && k < KPad) WT[(size_t)n * KPad + k] = f2b(T[r4 + i][c]);
    }
}

// ---------------- fc1 bias permute ----------------
__global__ __launch_bounds__(256) void bias_perm_kernel(const float* __restrict__ b,
        float* __restrict__ bp) {
    int r = blockIdx.x * 256 + threadIdx.x;
    if (r < 2 * HID_DIM) bp[r] = b[r < HID_DIM ? r + HID_DIM : r - HID_DIM];
}

// ---------------- 256x256 8-wave MFMA GEMM, 4-phase counted-vmcnt schedule ----------------
template<bool BF16OUT>
__global__ __launch_bounds__(512, 2) void gemm256(const us* __restrict__ A, int lda,
        const us* __restrict__ Bt, int ldb, const float* __restrict__ bias,
        const float* __restrict__ Rres, void* __restrict__ Cv,
        int M, int N, int K, int ldc) {
    __shared__ __align__(16) us lds[2][4][8192];
    us* const L = &lds[0][0][0];
    const int tid = threadIdx.x;
    const int lane = tid & 63;
    const int w = tid >> 6;
    const int wm = w >> 2, wn = w & 3;           // 2 x 4 wave grid, wave tile 128x64
    const int l15 = lane & 15, quad = lane >> 4;
    const int m0 = blockIdx.y * 256, n0 = blockIdx.x * 256;

    const int r0 = tid >> 3;
    const int c80 = (tid & 7) ^ (r0 & 7);
    const us* const pA = A + (size_t)(m0 + r0) * lda + c80 * 8;
    const us* const pB = Bt + (size_t)(n0 + r0) * ldb + c80 * 8;
    const size_t a64 = (size_t)64 * lda, b64 = (size_t)64 * ldb;
    us* const dst = L + tid * 8;

#define STG_A(b, h, kt) do { \
    const us* s_ = pA + (size_t)(h) * 2 * a64 + (size_t)(kt) * 64; \
    stage16(s_,       dst + ((b) * 4 + (h)) * 8192); \
    stage16(s_ + a64, dst + ((b) * 4 + (h)) * 8192 + 4096); \
} while (0)
#define STG_B(b, h, kt) do { \
    const us* s_ = pB + (size_t)(h) * 2 * b64 + (size_t)(kt) * 64; \
    stage16(s_,       dst + ((b) * 4 + 2 + (h)) * 8192); \
    stage16(s_ + b64, dst + ((b) * 4 + 2 + (h)) * 8192 + 4096); \
} while (0)

    f32x4 acc[8][4];
    #pragma unroll
    for (int m = 0; m < 8; m++)
        #pragma unroll
        for (int n = 0; n < 4; n++) acc[m][n] = (f32x4){0.f, 0.f, 0.f, 0.f};

    const int nk = K >> 6;

    STG_A(0, 0, 0); STG_A(0, 1, 0);
    STG_B(0, 0, 0); STG_B(0, 1, 0);
    STG_B(1, 0, 1); STG_B(1, 1, 1);
    asm volatile("s_waitcnt vmcnt(4)" ::: "memory");
    __builtin_amdgcn_s_barrier();

    const int brow = (wn & 1) * 64;
    for (int t = 0; t < nk; t++) {
        const int c = t & 1, cn = c ^ 1;
        const us* aB = L + (c * 4 + wm) * 8192;
        const us* bB = L + (c * 4 + 2 + (wn >> 1)) * 8192;
        short8 bf[4][2];
        #pragma unroll
        for (int n = 0; n < 4; n++) {
            bf[n][0] = *(const short8*)(bB + sl(brow + n * 16 + l15, quad));
            bf[n][1] = *(const short8*)(bB + sl(brow + n * 16 + l15, 4 + quad));
        }
        #pragma unroll
        for (int p = 0; p < 4; p++) {
            const int mp = 2 * p;
            short8 a00 = *(const short8*)(aB + sl(mp * 16 + l15, quad));
            short8 a01 = *(const short8*)(aB + sl(mp * 16 + l15, 4 + quad));
            short8 a10 = *(const short8*)(aB + sl(mp * 16 + 16 + l15, quad));
            short8 a11 = *(const short8*)(aB + sl(mp * 16 + 16 + l15, 4 + quad));
            if (p == 0) {
                if (t + 1 < nk) { STG_A(cn, 0, t + 1); STG_A(cn, 1, t + 1); }
            } else if (p == 1) {
                if (t + 2 < nk) STG_B(c, 0, t + 2);
            } else if (p == 2) {
                if (t + 2 < nk) STG_B(c, 1, t + 2);
            }
            __builtin_amdgcn_s_barrier();
            __builtin_amdgcn_s_setprio(1);
            #pragma unroll
            for (int n = 0; n < 4; n++) {
                acc[mp][n]     = MFMA16(a00, bf[n][0], acc[mp][n]);
                acc[mp][n]     = MFMA16(a01, bf[n][1], acc[mp][n]);
                acc[mp + 1][n] = MFMA16(a10, bf[n][0], acc[mp + 1][n]);
                acc[mp + 1][n] = MFMA16(a11, bf[n][1], acc[mp + 1][n]);
            }
            __builtin_amdgcn_s_setprio(0);
            if (p == 3) {
                if (t + 2 >= nk) { asm volatile("s_waitcnt vmcnt(0)" ::: "memory"); }
                else             { asm volatile("s_waitcnt vmcnt(4)" ::: "memory"); }
            }
            __builtin_amdgcn_s_barrier();
        }
    }

    #pragma unroll
    for (int m = 0; m < 8; m++) {
        int gm0 = m0 + wm * 128 + m * 16 + quad * 4;
        #pragma unroll
        for (int n = 0; n < 4; n++) {
            int gn = n0 + wn * 64 + n * 16 + l15;
            if (gn >= N) continue;
            float bs = bias[gn];
            #pragma unroll
            for (int r = 0; r < 4; r++) {
                int gm = gm0 + r;
                if (gm >= M) continue;
                float v = acc[m][n][r] + bs;
                if (BF16OUT) {
                    ((us*)Cv)[(size_t)gm * ldc + gn] = f2b(v);
                } else {
                    ((float*)Cv)[(size_t)gm * ldc + gn] = v + Rres[(size_t)gm * ldc + gn];
                }
            }
        }
    }
#undef STG_A
#undef STG_B
}

// ---------------- RoPE (in-place) + q*SCALE ----------------
__global__ __launch_bounds__(256) void rope_kernel(us* __restrict__ qkv) {
    int idx = blockIdx.x * 256 + threadIdx.x;
    int i = idx & 31;
    int h = (idx >> 5) & (NHEAD - 1);
    int rc = idx >> 9;
    int s = rc % S_DIM;
    us* q = qkv + (size_t)rc * 3072 + h * 64;
    us* k = q + 1024;
    if (s == 0) {
        q[i] = f2b(b2f(q[i]) * SCALE_V);
        q[i + 32] = f2b(b2f(q[i + 32]) * SCALE_V);
        return;
    }
    float pos = (float)(s - 1);
    float invf = expf((float)i * (-9.210340371976184f / 32.0f));
    float f = pos * invf;
    float c = cosf(f), sn = sinf(f);
    float q1 = b2f(q[i]), q2 = b2f(q[i + 32]);
    q[i]      = f2b((q1 * c - q2 * sn) * SCALE_V);
    q[i + 32] = f2b((q2 * c + q1 * sn) * SCALE_V);
    float k1 = b2f(k[i]), k2 = b2f(k[i + 32]);
    k[i]      = f2b(k1 * c - k2 * sn);
    k[i + 32] = f2b(k2 * c + k1 * sn);
}

// ---------------- V transpose ----------------
__global__ __launch_bounds__(256) void vtrans_kernel(const us* __restrict__ qkv,
        us* __restrict__ Vt) {
    __shared__ us T[64][65];
    int st = blockIdx.x, h = blockIdx.y, bc = blockIdx.z;
    int tid = threadIdx.x;
    int r = tid & 63, cb = (tid >> 6) * 16;
    const us* src = qkv + (size_t)(bc * S_DIM + st * 64 + r) * 3072 + 2048 + h * 64 + cb;
    #pragma unroll
    for (int i = 0; i < 4; i++) {
        ushort4 v = *(const ushort4*)(src + i * 4);
        T[cb + i*4 + 0][r] = v.x; T[cb + i*4 + 1][r] = v.y;
        T[cb + i*4 + 2][r] = v.z; T[cb + i*4 + 3][r] = v.w;
    }
    __syncthreads();
    int d = tid >> 2, sc = (tid & 3) * 16;
    us* dstp = Vt + ((size_t)((bc * 16 + h) * 64 + d)) * 1088 + st * 64 + sc;
    #pragma unroll
    for (int g = 0; g < 4; g++) {
        ushort4 o;
        int i0 = sc + g * 4;
        o.x = (st*64 + i0 + 0 < S_DIM) ? T[d][i0 + 0] : 0;
        o.y = (st*64 + i0 + 1 < S_DIM) ? T[d][i0 + 1] : 0;
        o.z = (st*64 + i0 + 2 < S_DIM) ? T[d][i0 + 2] : 0;
        o.w = (st*64 + i0 + 3 < S_DIM) ? T[d][i0 + 3] : 0;
        *(ushort4*)(dstp + g * 4) = o;
    }
}

// ---------------- MFMA flash attention, double-buffered K/V + reg-resident Q ----------------
// 2-phase pipeline: stage kt+1 at top, compute kt, single __syncthreads at bottom
// (drains this iter's stages; they hide under ~16 MFMA + softmax).
// Q fragments hoisted to registers (invariant across kt). Row-sum reduction moved
// out of the loop (per-lane partial l, uniform rescale). Defer-max THR=8 (T13).
__global__ __launch_bounds__(256) void attn_kernel(const us* __restrict__ qkv,
        const us* __restrict__ Vt, us* __restrict__ attnb) {
    __shared__ __align__(16) us Kb[2][4096];
    __shared__ __align__(16) us Vb[2][4096];
    __shared__ __align__(16) us Ps[4096];
    int qt = blockIdx.x, h = blockIdx.y, bc = blockIdx.z;
    int tid = threadIdx.x;
    int lane = tid & 63, w = tid >> 6;
    int l15 = lane & 15, quad = lane >> 4;

    // Q fragments direct global -> regs (same data the old LDS path delivered)
    const us* qrow = qkv + (size_t)(bc * S_DIM + qt * 64 + 16 * w + l15) * 3072 + h * 64;
    short8 qa0 = *(const short8*)(qrow + quad * 8);
    short8 qa1 = *(const short8*)(qrow + 32 + quad * 8);

    const us* kg = qkv + (size_t)(bc * S_DIM) * 3072 + 1024 + h * 64;
    const us* vgp = Vt + (size_t)((bc * 16 + h) * 64) * 1088;

    // staging slots (same swizzle as before)
    int s0 = tid, s1 = 256 + tid;
    int row0 = s0 >> 3, c8_0 = (s0 & 7) ^ (row0 & 7);
    int row1 = s1 >> 3, c8_1 = (s1 & 7) ^ (row1 & 7);

    f32x4 acc_o[4];
    float mr[4], lr[4];
    #pragma unroll
    for (int r = 0; r < 4; r++) { mr[r] = -1e30f; lr[r] = 0.f; }
    #pragma unroll
    for (int j = 0; j < 4; j++) acc_o[j] = (f32x4){0.f, 0.f, 0.f, 0.f};

    // prologue: stage tile 0 into buffer 0
    stage16(kg + (size_t)row0 * 3072 + c8_0 * 8, Kb[0] + s0 * 8);
    stage16(vgp + (size_t)row0 * 1088 + c8_0 * 8, Vb[0] + s0 * 8);
    stage16(kg + (size_t)row1 * 3072 + c8_1 * 8, Kb[0] + (s1 & 255) * 8 + 2048 * 8 * 0 + 256 * 8);
    // NOTE: slot s1 = 256+tid maps linearly: Kb[0] + s1*8
    // (rewritten below without the confusing arithmetic)
    stage16(vgp + (size_t)row1 * 1088 + c8_1 * 8, Vb[0] + s1 * 8);
    __syncthreads();

    for (int kt = 0; kt < 17; kt++) {
        int cur = kt & 1, nxt = cur ^ 1;
        if (kt + 1 < 17) {
            stage16(kg + (size_t)((kt + 1) * 64 + row0) * 3072 + c8_0 * 8, Kb[nxt] + s0 * 8);
            stage16(vgp + (size_t)row0 * 1088 + (kt + 1) * 64 + c8_0 * 8, Vb[nxt] + s0 * 8);
            stage16(kg + (size_t)((kt + 1) * 64 + row1) * 3072 + c8_1 * 8, Kb[nxt] + s1 * 8);
            stage16(vgp + (size_t)row1 * 1088 + (kt + 1) * 64 + c8_1 * 8, Vb[nxt] + s1 * 8);
        }

        f32x4 accS[4];
        #pragma unroll
        for (int j = 0; j < 4; j++) accS[j] = (f32x4){0.f, 0.f, 0.f, 0.f};
        __builtin_amdgcn_s_setprio(1);
        #pragma unroll
        for (int j = 0; j < 4; j++) {
            short8 kb0 = *(const short8*)(Kb[cur] + sl(16 * j + l15, quad));
            short8 kb1 = *(const short8*)(Kb[cur] + sl(16 * j + l15, 4 + quad));
            accS[j] = MFMA16(qa0, kb0, accS[j]);
            accS[j] = MFMA16(qa1, kb1, accS[j]);
        }
        __builtin_amdgcn_s_setprio(0);

        #pragma unroll
        for (int j = 0; j < 4; j++) {
            if (kt * 64 + 16 * j + l15 >= S_DIM) {
                #pragma unroll
                for (int r = 0; r < 4; r++) accS[j][r] = -1e30f;
            }
        }

        // tile max per query row (4 independent trees, 16-lane reduce)
        float tm[4];
        #pragma unroll
        for (int r = 0; r < 4; r++) {
            float t = fmaxf(fmaxf(accS[0][r], accS[1][r]), fmaxf(accS[2][r], accS[3][r]));
            #pragma unroll
            for (int off = 1; off < 16; off <<= 1)
                t = fmaxf(t, __shfl_xor(t, off, 64));
            tm[r] = t;
        }
        // defer-max (T13): rescale only if some row's max grew past THR=8
        int need = (tm[0] > mr[0] + 8.f) || (tm[1] > mr[1] + 8.f) ||
                   (tm[2] > mr[2] + 8.f) || (tm[3] > mr[3] + 8.f);
        if (__any(need)) {
            #pragma unroll
            for (int r = 0; r < 4; r++) {
                float mnew = fmaxf(mr[r], tm[r]);
                float al = __expf(mr[r] - mnew);
                mr[r] = mnew;
                lr[r] *= al;
                #pragma unroll
                for (int j = 0; j < 4; j++) acc_o[j][r] *= al;
            }
        }
        // P = exp(S - m); per-lane partial row-sum (full 16-lane reduce deferred to end)
        float pr[4][4];
        #pragma unroll
        for (int r = 0; r < 4; r++) {
            float rs = 0.f;
            #pragma unroll
            for (int j = 0; j < 4; j++) {
                float p = __expf(accS[j][r] - mr[r]);
                pr[j][r] = p;
                rs += p;
            }
            lr[r] += rs;
        }
        // pack P into wave-private Ps region (no barrier needed)
        #pragma unroll
        for (int j = 0; j < 4; j++) {
            #pragma unroll
            for (int r = 0; r < 4; r++) {
                int prow = quad * 4 + r;
                int idx = sl(16 * w + prow, 2 * j + (l15 >> 3)) + (l15 & 7);
                Ps[idx] = f2b(pr[j][r]);
            }
        }
        short8 pa0 = *(const short8*)(Ps + sl(16 * w + l15, quad));
        short8 pa1 = *(const short8*)(Ps + sl(16 * w + l15, 4 + quad));
        __builtin_amdgcn_s_setprio(1);
        #pragma unroll
        for (int j = 0; j < 4; j++) {
            short8 vb0 = *(const short8*)(Vb[cur] + sl(16 * j + l15, quad));
            short8 vb1 = *(const short8*)(Vb[cur] + sl(16 * j + l15, 4 + quad));
            acc_o[j] = MFMA16(pa0, vb0, acc_o[j]);
            acc_o[j] = MFMA16(pa1, vb1, acc_o[j]);
        }
        __builtin_amdgcn_s_setprio(0);
        __syncthreads();   // drains this iter's stages (vmcnt 0) + LDS; one barrier/iter
    }

    // final 16-lane row-sum reduce of the deferred partial l
    #pragma unroll
    for (int r = 0; r < 4; r++) {
        #pragma unroll
        for (int off = 1; off < 16; off <<= 1)
            lr[r] += __shfl_xor(lr[r], off, 64);
    }
    #pragma unroll
    for (int r = 0; r < 4; r++) {
        int s = qt * 64 + 16 * w + quad * 4 + r;
        if (s >= S_DIM) continue;
        float invl = 1.0f / lr[r];
        #pragma unroll
        for (int j = 0; j < 4; j++)
            attnb[(size_t)(bc * S_DIM + s) * E_DIM + h * 64 + 16 * j + l15] =
                f2b(acc_o[j][r] * invl);
    }
}

// ---------------- depthwise conv + GELU + gate ----------------
__global__ __launch_bounds__(256) void conv_gelu_kernel(us* __restrict__ hb,
        const float* __restrict__ dw_w, const float* __restrict__ dw_b) {
    int p = blockIdx.x % S_DIM;
    size_t row = blockIdx.x;
    size_t brow = row - p;
    for (int c = threadIdx.x; c < HID_DIM; c += 256) {
        float val;
        if (p == 0) {
            val = b2f(hb[row * HB_LD + HID_DIM + c]);
        } else {
            int pp = p - 1;
            int gy = pp >> 5, gx = pp & 31;
            float a = dw_b[c];
            #pragma unroll
            for (int dy = 0; dy < 3; dy++) {
                int ny = gy + dy - 1;
                if (ny < 0 || ny >= 32) continue;
                #pragma unroll
                for (int dx = 0; dx < 3; dx++) {
                    int nx = gx + dx - 1;
                    if (nx < 0 || nx >= 32) continue;
                    a = fmaf(b2f(hb[(brow + 1 + ny * 32 + nx) * HB_LD + HID_DIM + c]),
                             dw_w[(dy * 3 + dx) * HID_DIM + c], a);
                }
            }
            val = a;
        }
        float ge = 0.5f * val * (1.0f + erff(val * 0.70710678118654752f));
        hb[row * HB_LD + c] = f2b(ge * b2f(hb[row * HB_LD + c]));
    }
}

// ---------------- launch ----------------
static size_t ws_need(int cb) {
    size_t R = (size_t)cb * 1025, Rp = ((R + 127) / 128) * 128;
    size_t end1 = Rp*1024*2 + Rp*3072*2 + (size_t)cb*16*64*1088*2
                + 8320ull*1024*2 + 3072ull*1024*2 + 1024ull*1024*2;
    size_t end2 = Rp*1024*2 + Rp*HB_LD*2 + 5504ull*1024*2 + 1024ull*KP_FC2*2 + 5460*4;
    return end1 > end2 ? end1 : end2;
}

extern "C" void kernel_launch(void* const* d_in, const int* in_sizes, int n_in,
                              void* d_out, int out_size, void* d_ws, size_t ws_size,
                              hipStream_t stream) {
    const float* x      = (const float*)d_in[0];
    const float* g1     = (const float*)d_in[1];
    const float* w_qkv  = (const float*)d_in[2];
    const float* b_qkv  = (const float*)d_in[3];
    const float* w_proj = (const float*)d_in[4];
    const float* b_proj = (const float*)d_in[5];
    const float* g2     = (const float*)d_in[6];
    const float* fc1_w  = (const float*)d_in[7];
    const float* fc1_b  = (const float*)d_in[8];
    const float* dw_w   = (const float*)d_in[9];
    const float* dw_b   = (const float*)d_in[10];
    const float* fc2_w  = (const float*)d_in[11];
    const float* fc2_b  = (const float*)d_in[12];
    float* out = (float*)d_out;
    char* base = (char*)d_ws;

    int CB = 2;
    if (ws_size >= ws_need(8)) CB = 8;
    else if (ws_size >= ws_need(4)) CB = 4;
    int NC = B_DIM / CB;
    size_t R = (size_t)CB * 1025, Rp = ((R + 127) / 128) * 128;
    int gy256 = (int)((R + 255) / 256);

    // phase-1 layout
    us* xn    = (us*)base;                       // Rp x 1024
    size_t o  = Rp * 1024 * 2;
    us* qkv   = (us*)(base + o);                 // Rp x 3072 (phase1)
    us* hbuf  = (us*)(base + o);                 // Rp x HB_LD (phase2 overlay)
    size_t o2 = o + Rp * 3072 * 2;
    us* Vt    = (us*)(base + o2);                // CB x 16 x 64 x 1088
    size_t o3 = o2 + (size_t)CB * 16 * 64 * 1088 * 2;
    us* attnb = (us*)(base + o3);                // 8320 x 1024
    size_t o4 = o3 + 8320ull * 1024 * 2;
    us* qkvT  = (us*)(base + o4);                // 3072 x 1024
    size_t o5 = o4 + 3072ull * 1024 * 2;
    us* projT = (us*)(base + o5);                // 1024 x 1024
    // phase-2 layout (overlays qkv/Vt/attnb/qkvT/projT)
    size_t p2 = o + Rp * HB_LD * 2;
    us* fc1T  = (us*)(base + p2);                // 5504 x 1024
    size_t p3 = p2 + 5504ull * 1024 * 2;
    us* fc2T  = (us*)(base + p3);                // 1024 x KP_FC2
    float* fc1bp = (float*)(base + p3 + 1024ull * KP_FC2 * 2);   // 5460 f32

    // ---- attention phase ----
    convt_kernel<<<dim3(96, 32), 256, 0, stream>>>(w_qkv, qkvT, 1024, 3072, 1024, 0);
    convt_kernel<<<dim3(32, 32), 256, 0, stream>>>(w_proj, projT, 1024, 1024, 1024, 0);
    for (int c = 0; c < NC; c++) {
        size_t roff = (size_t)c * R;
        rmsnorm_kernel<<<(int)R, 256, 0, stream>>>(x + roff * E_DIM, g1, xn);
        gemm256<true><<<dim3(12, gy256), 512, 0, stream>>>(xn, 1024, qkvT, 1024,
                b_qkv, nullptr, qkv, (int)R, 3072, 1024, 3072);
        rope_kernel<<<(int)(2 * R), 256, 0, stream>>>(qkv);
        vtrans_kernel<<<dim3(17, 16, CB), 256, 0, stream>>>(qkv, Vt);
        attn_kernel<<<dim3(17, 16, CB), 256, 0, stream>>>(qkv, Vt, attnb + roff * E_DIM);
    }
    gemm256<false><<<dim3(4, (MROWS + 255) / 256), 512, 0, stream>>>(attnb, 1024,
            projT, 1024, b_proj, x, out, MROWS, 1024, 1024, 1024);

    // ---- MLP phase ----
    convt_kernel<<<dim3(171, 32), 256, 0, stream>>>(fc1_w, fc1T, 1024, 5460, 1024, HID_DIM);
    convt_kernel<<<dim3(32, 86), 256, 0, stream>>>(fc2_w, fc2T, HID_DIM, 1024, KP_FC2, 0);
    bias_perm_kernel<<<22, 256, 0, stream>>>(fc1_b, fc1bp);
    for (int c = 0; c < NC; c++) {
        size_t roff = (size_t)c * R;
        float* outc = out + roff * E_DIM;
        rmsnorm_kernel<<<(int)R, 256, 0, stream>>>(outc, g2, xn);
        gemm256<true><<<dim3(22, gy256), 512, 0, stream>>>(xn, 1024, fc1T, 1024,
                fc1bp, nullptr, hbuf, (int)R, 5460, 1024, HB_LD);
        conv_gelu_kernel<<<(int)R, 256, 0, stream>>>(hbuf, dw_w, dw_b);
        gemm256<false><<<dim3(4, gy256), 512, 0, stream>>>(hbuf, HB_LD, fc2T, KP_FC2,
                fc2_b, outc, outc, (int)R, 1024, KP_FC2, 1024);
    }
}

// Round 4
// 813.963 us; speedup vs baseline: 1.3368x; 1.0335x over previous
//
#include <hip/hip_runtime.h>
#include <hip/hip_bf16.h>
#include <math.h>

#define E_DIM 1024
#define NHEAD 16
#define HID_DIM 2730
#define KP_FC2 2752            // fc2 K padded (zero weight rows) -> mult of 64
#define HB_LD 5504             // hbuf row stride (16B-aligned)
#define XG_OFF 2752            // xg half starts here (16B-aligned); cols [2730,2752) are 0
#define FC1_N 5482             // 2730 vg + 22 zero + 2730 xg
#define B_DIM 8
#define S_DIM 1025
#define EPS_V 1e-6f
#define SCALE_V 0.125f
#define MROWS (B_DIM * S_DIM)   // 8200

typedef __attribute__((ext_vector_type(8))) short short8;
typedef __attribute__((ext_vector_type(4))) float f32x4;
typedef unsigned short us;

__device__ __forceinline__ float b2f(us u) {
    union { unsigned int i; float f; } x; x.i = ((unsigned int)u) << 16; return x.f;
}
__device__ __forceinline__ us f2b(float f) {
    __hip_bfloat16 h = __float2bfloat16(f);
    return *reinterpret_cast<us*>(&h);
}

__device__ __forceinline__ void stage16(const void* g, void* l) {
    __builtin_amdgcn_global_load_lds(
        (const __attribute__((address_space(1))) unsigned int*)g,
        (__attribute__((address_space(3))) unsigned int*)l,
        16, 0, 0);
}

// u16 index of the 8-element group at (row, c8) in a XOR-swizzled [R][64] bf16 tile
__device__ __forceinline__ int sl(int row, int c8) {
    return (row * 8 + (c8 ^ (row & 7))) * 8;
}

#define MFMA16(a, b, c) __builtin_amdgcn_mfma_f32_16x16x32_bf16(a, b, c, 0, 0, 0)

// ---------------- RMSNorm (fp32 in -> bf16 out) ----------------
__global__ __launch_bounds__(256) void rmsnorm_kernel(const float* __restrict__ x,
        const float* __restrict__ g, us* __restrict__ out) {
    int row = blockIdx.x;
    const float4* xr = (const float4*)(x + (size_t)row * E_DIM);
    float4 v = xr[threadIdx.x];
    float ss = v.x*v.x + v.y*v.y + v.z*v.z + v.w*v.w;
    #pragma unroll
    for (int off = 32; off > 0; off >>= 1) ss += __shfl_down(ss, off, 64);
    __shared__ float wsum[4];
    int lane = threadIdx.x & 63, w = threadIdx.x >> 6;
    if (lane == 0) wsum[w] = ss;
    __syncthreads();
    float tot = wsum[0] + wsum[1] + wsum[2] + wsum[3];
    float inv = rsqrtf(tot * (1.0f / E_DIM) + EPS_V);
    float4 gv = ((const float4*)g)[threadIdx.x];
    ushort4 o;
    o.x = f2b(v.x * inv * gv.x); o.y = f2b(v.y * inv * gv.y);
    o.z = f2b(v.z * inv * gv.z); o.w = f2b(v.w * inv * gv.w);
    ((ushort4*)(out + (size_t)row * E_DIM))[threadIdx.x] = o;
}

// ---------------- weight convert+transpose: W[K][Wld] f32 -> WT[n][k] bf16 ----------------
// N = output row count; Wld = SOURCE row stride (true width of W).  [round-3 bug: N was
// used as both -> fc1 weights read 22*k elements off. Now separate.]
// swap_half != 0: row n sources col n+swap_half (n<swap_half), col n-xg_off (n>=xg_off), else 0.
__global__ __launch_bounds__(256) void convt_kernel(const float* __restrict__ W,
        us* __restrict__ WT, int K, int N, int KPad, int swap_half, int xg_off, int Wld) {
    __shared__ float T[32][33];
    int n0 = blockIdx.x * 32, k0 = blockIdx.y * 32;
    int c = threadIdx.x & 31, r4 = (threadIdx.x >> 5) << 2;
    #pragma unroll
    for (int i = 0; i < 4; i++) {
        int k = k0 + r4 + i, n = n0 + c;
        float v = 0.0f;
        if (k < K && n < N) {
            int src = n;
            int ok = 1;
            if (swap_half) {
                if (n < swap_half) src = n + swap_half;
                else if (xg_off) { if (n >= xg_off) src = n - xg_off; else ok = 0; }
                else src = n - swap_half;
            }
            if (ok) v = W[(size_t)k * Wld + src];
        }
        T[c][r4 + i] = v;
    }
    __syncthreads();
    #pragma unroll
    for (int i = 0; i < 4; i++) {
        int n = n0 + r4 + i, k = k0 + c;
        if (n < N && k < KPad) WT[(size_t)n * KPad + k] = f2b(T[r4 + i][c]);
    }
}

// ---------------- fc1 bias permute (vg | 22 zeros | xg) ----------------
__global__ __launch_bounds__(256) void bias_perm_kernel(const float* __restrict__ b,
        float* __restrict__ bp) {
    int r = blockIdx.x * 256 + threadIdx.x;
    if (r < FC1_N)
        bp[r] = (r < HID_DIM) ? b[r + HID_DIM] : ((r < XG_OFF) ? 0.0f : b[r - XG_OFF]);
}

// ---------------- 256x256 8-wave MFMA GEMM, balanced 4-phase counted-vmcnt ----------------
// MODE 0: bf16 out = acc+bias; MODE 1: f32 out = acc+bias+Rres;
// MODE 2: atomicAdd f32 (K-split over blockIdx.z; bias added by z==0 only).
template<int MODE>
__global__ __launch_bounds__(512, 2) void gemm256(const us* __restrict__ A, int lda,
        const us* __restrict__ Bt, int ldb, const float* __restrict__ bias,
        const float* __restrict__ Rres, void* __restrict__ Cv,
        int M, int N, int K, int ldc, int Ksplit) {
    __shared__ __align__(16) us lds[2][4][8192];
    us* const L = &lds[0][0][0];
    const int tid = threadIdx.x;
    const int lane = tid & 63;
    const int w = tid >> 6;
    const int wm = w >> 2, wn = w & 3;           // 2 x 4 wave grid, wave tile 128x64
    const int l15 = lane & 15, quad = lane >> 4;

    // T1: XCD-aware bijective block swizzle (m204)
    const int nwg = gridDim.x * gridDim.y;
    const int orig = blockIdx.y * gridDim.x + blockIdx.x;
    const int q8 = nwg >> 3, r8 = nwg & 7;
    const int xcd = orig & 7, oi = orig >> 3;
    const int wgid = (xcd < r8 ? xcd * (q8 + 1) : r8 * (q8 + 1) + (xcd - r8) * q8) + oi;
    const int m0 = (wgid / gridDim.x) * 256, n0 = (wgid % gridDim.x) * 256;

    const int kz = (MODE == 2) ? (int)blockIdx.z : 0;
    const int kofs = kz * Ksplit;
    const int Keff = (MODE == 2) ? (kz ? K - Ksplit : Ksplit) : K;

    const int r0 = tid >> 3;
    const int c80 = (tid & 7) ^ (r0 & 7);
    const us* const pA = A + (size_t)(m0 + r0) * lda + kofs + c80 * 8;
    const us* const pB = Bt + (size_t)(n0 + r0) * ldb + kofs + c80 * 8;
    const size_t a64 = (size_t)64 * lda, b64 = (size_t)64 * ldb;
    us* const dst = L + tid * 8;

#define STG_A(b, h, kt) do { \
    const us* s_ = pA + (size_t)(h) * 2 * a64 + (size_t)(kt) * 64; \
    stage16(s_,       dst + ((b) * 4 + (h)) * 8192); \
    stage16(s_ + a64, dst + ((b) * 4 + (h)) * 8192 + 4096); \
} while (0)
#define STG_B(b, h, kt) do { \
    const us* s_ = pB + (size_t)(h) * 2 * b64 + (size_t)(kt) * 64; \
    stage16(s_,       dst + ((b) * 4 + 2 + (h)) * 8192); \
    stage16(s_ + b64, dst + ((b) * 4 + 2 + (h)) * 8192 + 4096); \
} while (0)

    f32x4 acc[8][4];
    #pragma unroll
    for (int m = 0; m < 8; m++)
        #pragma unroll
        for (int n = 0; n < 4; n++) acc[m][n] = (f32x4){0.f, 0.f, 0.f, 0.f};

    const int nk = Keff >> 6;
    const int brow = (wn & 1) * 64;

    // prologue: tile0 + tile1 staged; drain tile0; barrier publishes
    STG_A(0, 0, 0); STG_A(0, 1, 0);
    STG_B(0, 0, 0); STG_B(0, 1, 0);
    if (nk > 1) {
        STG_B(1, 0, 1); STG_B(1, 1, 1);
        STG_A(1, 0, 1); STG_A(1, 1, 1);
        asm volatile("s_waitcnt vmcnt(8)" ::: "memory");
    } else {
        asm volatile("s_waitcnt vmcnt(0)" ::: "memory");
    }
    __builtin_amdgcn_s_barrier();
    __builtin_amdgcn_sched_barrier(0);

    short8 bf01[2][2];
    {
        const us* bB0 = L + (2 + (wn >> 1)) * 8192;
        #pragma unroll
        for (int n = 0; n < 2; n++) {
            bf01[n][0] = *(const short8*)(bB0 + sl(brow + n * 16 + l15, quad));
            bf01[n][1] = *(const short8*)(bB0 + sl(brow + n * 16 + l15, 4 + quad));
        }
    }

    for (int t = 0; t < nk; t++) {
        const int c = t & 1, cn = c ^ 1;
        const us* aB = L + (c * 4 + wm) * 8192;
        const us* bB = L + (c * 4 + 2 + (wn >> 1)) * 8192;
        const us* bBn = L + (cn * 4 + 2 + (wn >> 1)) * 8192;
        short8 bf2[2][2];
        #pragma unroll
        for (int n = 0; n < 2; n++) {
            bf2[n][0] = *(const short8*)(bB + sl(brow + (n + 2) * 16 + l15, quad));
            bf2[n][1] = *(const short8*)(bB + sl(brow + (n + 2) * 16 + l15, 4 + quad));
        }
        #pragma unroll
        for (int p = 0; p < 4; p++) {
            const int mp = 2 * p;
            short8 a00 = *(const short8*)(aB + sl(mp * 16 + l15, quad));
            short8 a01 = *(const short8*)(aB + sl(mp * 16 + l15, 4 + quad));
            short8 a10 = *(const short8*)(aB + sl(mp * 16 + 16 + l15, quad));
            short8 a11 = *(const short8*)(aB + sl(mp * 16 + 16 + l15, 4 + quad));
            if (p == 1) { if (t + 2 < nk) STG_B(c, 0, t + 2); }
            else if (p == 2) { if (t + 2 < nk) STG_B(c, 1, t + 2); }
            else if (p == 3) {
                // counted drain of A(t+1)+B(t+1) BEFORE the barrier -> barrier publishes
                if (t + 2 < nk)      { asm volatile("s_waitcnt vmcnt(4)" ::: "memory"); }
                else if (t + 1 < nk) { asm volatile("s_waitcnt vmcnt(0)" ::: "memory"); }
            }
            __builtin_amdgcn_s_barrier();
            if (p == 3) __builtin_amdgcn_sched_barrier(0);   // pin early-reads below barrier
            __builtin_amdgcn_s_setprio(1);
            #pragma unroll
            for (int n = 0; n < 4; n++) {
                const short8 b0 = (n < 2) ? bf01[n][0] : bf2[n - 2][0];
                const short8 b1 = (n < 2) ? bf01[n][1] : bf2[n - 2][1];
                acc[mp][n]     = MFMA16(a00, b0, acc[mp][n]);
                acc[mp][n]     = MFMA16(a01, b1, acc[mp][n]);
                acc[mp + 1][n] = MFMA16(a10, b0, acc[mp + 1][n]);
                acc[mp + 1][n] = MFMA16(a11, b1, acc[mp + 1][n]);
            }
            __builtin_amdgcn_s_setprio(0);
            if (p == 3) {
                if (t + 2 < nk) { STG_A(c, 0, t + 2); STG_A(c, 1, t + 2); }
                if (t + 1 < nk) {   // early-read next tile's B n=0,1 (published at barrier above)
                    #pragma unroll
                    for (int n = 0; n < 2; n++) {
                        bf01[n][0] = *(const short8*)(bBn + sl(brow + n * 16 + l15, quad));
                        bf01[n][1] = *(const short8*)(bBn + sl(brow + n * 16 + l15, 4 + quad));
                    }
                }
            }
            __builtin_amdgcn_s_barrier();
            if (p == 3) __builtin_amdgcn_sched_barrier(0);   // no next-iter reads above this
        }
    }

    // epilogue
    #pragma unroll
    for (int m = 0; m < 8; m++) {
        int gm0 = m0 + wm * 128 + m * 16 + quad * 4;
        #pragma unroll
        for (int n = 0; n < 4; n++) {
            int gn = n0 + wn * 64 + n * 16 + l15;
            if (gn >= N) continue;
            float bs = (MODE == 2) ? (kz == 0 ? bias[gn] : 0.0f) : bias[gn];
            #pragma unroll
            for (int r = 0; r < 4; r++) {
                int gm = gm0 + r;
                if (gm >= M) continue;
                float v = acc[m][n][r] + bs;
                if (MODE == 0) {
                    ((us*)Cv)[(size_t)gm * ldc + gn] = f2b(v);
                } else if (MODE == 1) {
                    ((float*)Cv)[(size_t)gm * ldc + gn] = v + Rres[(size_t)gm * ldc + gn];
                } else {
                    atomicAdd(&((float*)Cv)[(size_t)gm * ldc + gn], v);
                }
            }
        }
    }
#undef STG_A
#undef STG_B
}

// ---------------- RoPE (in-place) + q*SCALE ----------------
__global__ __launch_bounds__(256) void rope_kernel(us* __restrict__ qkv) {
    int idx = blockIdx.x * 256 + threadIdx.x;
    int i = idx & 31;
    int h = (idx >> 5) & (NHEAD - 1);
    int rc = idx >> 9;
    int s = rc % S_DIM;
    us* q = qkv + (size_t)rc * 3072 + h * 64;
    us* k = q + 1024;
    if (s == 0) {
        q[i] = f2b(b2f(q[i]) * SCALE_V);
        q[i + 32] = f2b(b2f(q[i + 32]) * SCALE_V);
        return;
    }
    float pos = (float)(s - 1);
    float invf = expf((float)i * (-9.210340371976184f / 32.0f));
    float f = pos * invf;
    float c = cosf(f), sn = sinf(f);
    float q1 = b2f(q[i]), q2 = b2f(q[i + 32]);
    q[i]      = f2b((q1 * c - q2 * sn) * SCALE_V);
    q[i + 32] = f2b((q2 * c + q1 * sn) * SCALE_V);
    float k1 = b2f(k[i]), k2 = b2f(k[i + 32]);
    k[i]      = f2b(k1 * c - k2 * sn);
    k[i + 32] = f2b(k2 * c + k1 * sn);
}

// ---------------- V transpose ----------------
__global__ __launch_bounds__(256) void vtrans_kernel(const us* __restrict__ qkv,
        us* __restrict__ Vt) {
    __shared__ us T[64][65];
    int st = blockIdx.x, h = blockIdx.y, bc = blockIdx.z;
    int tid = threadIdx.x;
    int r = tid & 63, cb = (tid >> 6) * 16;
    const us* src = qkv + (size_t)(bc * S_DIM + st * 64 + r) * 3072 + 2048 + h * 64 + cb;
    #pragma unroll
    for (int i = 0; i < 4; i++) {
        ushort4 v = *(const ushort4*)(src + i * 4);
        T[cb + i*4 + 0][r] = v.x; T[cb + i*4 + 1][r] = v.y;
        T[cb + i*4 + 2][r] = v.z; T[cb + i*4 + 3][r] = v.w;
    }
    __syncthreads();
    int d = tid >> 2, sc = (tid & 3) * 16;
    us* dstp = Vt + ((size_t)((bc * 16 + h) * 64 + d)) * 1088 + st * 64 + sc;
    #pragma unroll
    for (int g = 0; g < 4; g++) {
        ushort4 o;
        int i0 = sc + g * 4;
        o.x = (st*64 + i0 + 0 < S_DIM) ? T[d][i0 + 0] : 0;
        o.y = (st*64 + i0 + 1 < S_DIM) ? T[d][i0 + 1] : 0;
        o.z = (st*64 + i0 + 2 < S_DIM) ? T[d][i0 + 2] : 0;
        o.w = (st*64 + i0 + 3 < S_DIM) ? T[d][i0 + 3] : 0;
        *(ushort4*)(dstp + g * 4) = o;
    }
}

// ---------------- MFMA flash attention (round-2 proven) ----------------
__global__ __launch_bounds__(256) void attn_kernel(const us* __restrict__ qkv,
        const us* __restrict__ Vt, us* __restrict__ attnb) {
    __shared__ __align__(16) us Kb[2][4096];
    __shared__ __align__(16) us Vb[2][4096];
    __shared__ __align__(16) us Ps[4096];
    int qt = blockIdx.x, h = blockIdx.y, bc = blockIdx.z;
    int tid = threadIdx.x;
    int lane = tid & 63, w = tid >> 6;
    int l15 = lane & 15, quad = lane >> 4;

    const us* qrow = qkv + (size_t)(bc * S_DIM + qt * 64 + 16 * w + l15) * 3072 + h * 64;
    short8 qa0 = *(const short8*)(qrow + quad * 8);
    short8 qa1 = *(const short8*)(qrow + 32 + quad * 8);

    const us* kg = qkv + (size_t)(bc * S_DIM) * 3072 + 1024 + h * 64;
    const us* vgp = Vt + (size_t)((bc * 16 + h) * 64) * 1088;

    int s0 = tid, s1 = 256 + tid;
    int row0 = s0 >> 3, c8_0 = (s0 & 7) ^ (row0 & 7);
    int row1 = s1 >> 3, c8_1 = (s1 & 7) ^ (row1 & 7);

    f32x4 acc_o[4];
    float mr[4], lr[4];
    #pragma unroll
    for (int r = 0; r < 4; r++) { mr[r] = -1e30f; lr[r] = 0.f; }
    #pragma unroll
    for (int j = 0; j < 4; j++) acc_o[j] = (f32x4){0.f, 0.f, 0.f, 0.f};

    stage16(kg + (size_t)row0 * 3072 + c8_0 * 8, Kb[0] + s0 * 8);
    stage16(vgp + (size_t)row0 * 1088 + c8_0 * 8, Vb[0] + s0 * 8);
    stage16(kg + (size_t)row1 * 3072 + c8_1 * 8, Kb[0] + s1 * 8);
    stage16(vgp + (size_t)row1 * 1088 + c8_1 * 8, Vb[0] + s1 * 8);
    __syncthreads();

    for (int kt = 0; kt < 17; kt++) {
        int cur = kt & 1, nxt = cur ^ 1;
        if (kt + 1 < 17) {
            stage16(kg + (size_t)((kt + 1) * 64 + row0) * 3072 + c8_0 * 8, Kb[nxt] + s0 * 8);
            stage16(vgp + (size_t)row0 * 1088 + (kt + 1) * 64 + c8_0 * 8, Vb[nxt] + s0 * 8);
            stage16(kg + (size_t)((kt + 1) * 64 + row1) * 3072 + c8_1 * 8, Kb[nxt] + s1 * 8);
            stage16(vgp + (size_t)row1 * 1088 + (kt + 1) * 64 + c8_1 * 8, Vb[nxt] + s1 * 8);
        }

        f32x4 accS[4];
        #pragma unroll
        for (int j = 0; j < 4; j++) accS[j] = (f32x4){0.f, 0.f, 0.f, 0.f};
        __builtin_amdgcn_s_setprio(1);
        #pragma unroll
        for (int j = 0; j < 4; j++) {
            short8 kb0 = *(const short8*)(Kb[cur] + sl(16 * j + l15, quad));
            short8 kb1 = *(const short8*)(Kb[cur] + sl(16 * j + l15, 4 + quad));
            accS[j] = MFMA16(qa0, kb0, accS[j]);
            accS[j] = MFMA16(qa1, kb1, accS[j]);
        }
        __builtin_amdgcn_s_setprio(0);

        #pragma unroll
        for (int j = 0; j < 4; j++) {
            if (kt * 64 + 16 * j + l15 >= S_DIM) {
                #pragma unroll
                for (int r = 0; r < 4; r++) accS[j][r] = -1e30f;
            }
        }

        float tm[4];
        #pragma unroll
        for (int r = 0; r < 4; r++) {
            float t = fmaxf(fmaxf(accS[0][r], accS[1][r]), fmaxf(accS[2][r], accS[3][r]));
            #pragma unroll
            for (int off = 1; off < 16; off <<= 1)
                t = fmaxf(t, __shfl_xor(t, off, 64));
            tm[r] = t;
        }
        int need = (tm[0] > mr[0] + 8.f) || (tm[1] > mr[1] + 8.f) ||
                   (tm[2] > mr[2] + 8.f) || (tm[3] > mr[3] + 8.f);
        if (__any(need)) {
            #pragma unroll
            for (int r = 0; r < 4; r++) {
                float mnew = fmaxf(mr[r], tm[r]);
                float al = __expf(mr[r] - mnew);
                mr[r] = mnew;
                lr[r] *= al;
                #pragma unroll
                for (int j = 0; j < 4; j++) acc_o[j][r] *= al;
            }
        }
        float pr[4][4];
        #pragma unroll
        for (int r = 0; r < 4; r++) {
            float rs = 0.f;
            #pragma unroll
            for (int j = 0; j < 4; j++) {
                float p = __expf(accS[j][r] - mr[r]);
                pr[j][r] = p;
                rs += p;
            }
            lr[r] += rs;
        }
        #pragma unroll
        for (int j = 0; j < 4; j++) {
            #pragma unroll
            for (int r = 0; r < 4; r++) {
                int prow = quad * 4 + r;
                int idx = sl(16 * w + prow, 2 * j + (l15 >> 3)) + (l15 & 7);
                Ps[idx] = f2b(pr[j][r]);
            }
        }
        short8 pa0 = *(const short8*)(Ps + sl(16 * w + l15, quad));
        short8 pa1 = *(const short8*)(Ps + sl(16 * w + l15, 4 + quad));
        __builtin_amdgcn_s_setprio(1);
        #pragma unroll
        for (int j = 0; j < 4; j++) {
            short8 vb0 = *(const short8*)(Vb[cur] + sl(16 * j + l15, quad));
            short8 vb1 = *(const short8*)(Vb[cur] + sl(16 * j + l15, 4 + quad));
            acc_o[j] = MFMA16(pa0, vb0, acc_o[j]);
            acc_o[j] = MFMA16(pa1, vb1, acc_o[j]);
        }
        __builtin_amdgcn_s_setprio(0);
        __syncthreads();
    }

    #pragma unroll
    for (int r = 0; r < 4; r++) {
        #pragma unroll
        for (int off = 1; off < 16; off <<= 1)
            lr[r] += __shfl_xor(lr[r], off, 64);
    }
    #pragma unroll
    for (int r = 0; r < 4; r++) {
        int s = qt * 64 + 16 * w + quad * 4 + r;
        if (s >= S_DIM) continue;
        float invl = 1.0f / lr[r];
        #pragma unroll
        for (int j = 0; j < 4; j++)
            attnb[(size_t)(bc * S_DIM + s) * E_DIM + h * 64 + 16 * j + l15] =
                f2b(acc_o[j][r] * invl);
    }
}

// ---------------- depthwise conv + GELU + gate, vectorized (xg at XG_OFF, 16B-aligned) ----
__global__ __launch_bounds__(256) void conv_gelu_kernel(us* __restrict__ hb,
        const float* __restrict__ dw_w, const float* __restrict__ dw_b) {
    int p = blockIdx.x % S_DIM;
    size_t row = blockIdx.x;
    size_t brow = row - p;
    int pp = p - 1;
    int gy = pp >> 5, gx = pp & 31;
    for (int g = threadIdx.x; g < 342; g += 256) {
        int c0 = g * 8;
        if (c0 + 8 <= HID_DIM) {
            float val[8];
            if (p == 0) {
                short8 xv = *(const short8*)(hb + row * HB_LD + XG_OFF + c0);
                #pragma unroll
                for (int e = 0; e < 8; e++) val[e] = b2f((us)xv[e]);
            } else {
                #pragma unroll
                for (int e = 0; e < 8; e++) val[e] = dw_b[c0 + e];
                #pragma unroll
                for (int dy = 0; dy < 3; dy++) {
                    int ny = gy + dy - 1;
                    if (ny < 0 || ny >= 32) continue;
                    #pragma unroll
                    for (int dx = 0; dx < 3; dx++) {
                        int nx = gx + dx - 1;
                        if (nx < 0 || nx >= 32) continue;
                        short8 xv = *(const short8*)(hb +
                                (brow + 1 + ny * 32 + nx) * HB_LD + XG_OFF + c0);
                        const float* wp = dw_w + (dy * 3 + dx) * HID_DIM + c0;
                        float2 w0 = *(const float2*)(wp);
                        float2 w1 = *(const float2*)(wp + 2);
                        float2 w2 = *(const float2*)(wp + 4);
                        float2 w3 = *(const float2*)(wp + 6);
                        val[0] = fmaf(b2f((us)xv[0]), w0.x, val[0]);
                        val[1] = fmaf(b2f((us)xv[1]), w0.y, val[1]);
                        val[2] = fmaf(b2f((us)xv[2]), w1.x, val[2]);
                        val[3] = fmaf(b2f((us)xv[3]), w1.y, val[3]);
                        val[4] = fmaf(b2f((us)xv[4]), w2.x, val[4]);
                        val[5] = fmaf(b2f((us)xv[5]), w2.y, val[5]);
                        val[6] = fmaf(b2f((us)xv[6]), w3.x, val[6]);
                        val[7] = fmaf(b2f((us)xv[7]), w3.y, val[7]);
                    }
                }
            }
            short8 gv = *(const short8*)(hb + row * HB_LD + c0);
            short8 o;
            #pragma unroll
            for (int e = 0; e < 8; e++) {
                float ge = 0.5f * val[e] * (1.0f + erff(val[e] * 0.70710678118654752f));
                o[e] = (short)f2b(ge * b2f((us)gv[e]));
            }
            *(short8*)(hb + row * HB_LD + c0) = o;
        } else {
            for (int c = c0; c < HID_DIM; c++) {
                float val;
                if (p == 0) {
                    val = b2f(hb[row * HB_LD + XG_OFF + c]);
                } else {
                    float a = dw_b[c];
                    #pragma unroll
                    for (int dy = 0; dy < 3; dy++) {
                        int ny = gy + dy - 1;
                        if (ny < 0 || ny >= 32) continue;
                        #pragma unroll
                        for (int dx = 0; dx < 3; dx++) {
                            int nx = gx + dx - 1;
                            if (nx < 0 || nx >= 32) continue;
                            a = fmaf(b2f(hb[(brow + 1 + ny * 32 + nx) * HB_LD + XG_OFF + c]),
                                     dw_w[(dy * 3 + dx) * HID_DIM + c], a);
                        }
                    }
                    val = a;
                }
                float ge = 0.5f * val * (1.0f + erff(val * 0.70710678118654752f));
                hb[row * HB_LD + c] = f2b(ge * b2f(hb[row * HB_LD + c]));
            }
        }
    }
}

// ---------------- launch ----------------
static size_t ws_need(int cb) {
    size_t R = (size_t)cb * 1025, Rp = ((R + 127) / 128) * 128;
    size_t end1 = Rp*1024*2 + Rp*3072*2 + (size_t)cb*16*64*1088*2
                + 8320ull*1024*2 + 3072ull*1024*2 + 1024ull*1024*2;
    size_t end2 = Rp*1024*2 + Rp*HB_LD*2 + 5504ull*1024*2 + 1024ull*KP_FC2*2 + 5504*4;
    return end1 > end2 ? end1 : end2;
}

extern "C" void kernel_launch(void* const* d_in, const int* in_sizes, int n_in,
                              void* d_out, int out_size, void* d_ws, size_t ws_size,
                              hipStream_t stream) {
    const float* x      = (const float*)d_in[0];
    const float* g1     = (const float*)d_in[1];
    const float* w_qkv  = (const float*)d_in[2];
    const float* b_qkv  = (const float*)d_in[3];
    const float* w_proj = (const float*)d_in[4];
    const float* b_proj = (const float*)d_in[5];
    const float* g2     = (const float*)d_in[6];
    const float* fc1_w  = (const float*)d_in[7];
    const float* fc1_b  = (const float*)d_in[8];
    const float* dw_w   = (const float*)d_in[9];
    const float* dw_b   = (const float*)d_in[10];
    const float* fc2_w  = (const float*)d_in[11];
    const float* fc2_b  = (const float*)d_in[12];
    float* out = (float*)d_out;
    char* base = (char*)d_ws;

    int CB = 2;
    if (ws_size >= ws_need(8)) CB = 8;
    else if (ws_size >= ws_need(4)) CB = 4;
    int NC = B_DIM / CB;
    size_t R = (size_t)CB * 1025, Rp = ((R + 127) / 128) * 128;
    int gy256 = (int)((R + 255) / 256);

    // phase-1 layout
    us* xn    = (us*)base;                       // Rp x 1024
    size_t o  = Rp * 1024 * 2;
    us* qkv   = (us*)(base + o);                 // Rp x 3072 (phase1)
    us* hbuf  = (us*)(base + o);                 // Rp x HB_LD (phase2 overlay)
    size_t o2 = o + Rp * 3072 * 2;
    us* Vt    = (us*)(base + o2);                // CB x 16 x 64 x 1088
    size_t o3 = o2 + (size_t)CB * 16 * 64 * 1088 * 2;
    us* attnb = (us*)(base + o3);                // 8320 x 1024
    size_t o4 = o3 + 8320ull * 1024 * 2;
    us* qkvT  = (us*)(base + o4);                // 3072 x 1024
    size_t o5 = o4 + 3072ull * 1024 * 2;
    us* projT = (us*)(base + o5);                // 1024 x 1024
    // phase-2 layout (overlays qkv/Vt/attnb/qkvT/projT)
    size_t p2 = o + Rp * HB_LD * 2;
    us* fc1T  = (us*)(base + p2);                // 5504 x 1024
    size_t p3 = p2 + 5504ull * 1024 * 2;
    us* fc2T  = (us*)(base + p3);                // 1024 x KP_FC2
    float* fc1bp = (float*)(base + p3 + 1024ull * KP_FC2 * 2);   // 5504 f32

    // ---- attention phase ----
    convt_kernel<<<dim3(96, 32), 256, 0, stream>>>(w_qkv, qkvT, 1024, 3072, 1024, 0, 0, 3072);
    convt_kernel<<<dim3(32, 32), 256, 0, stream>>>(w_proj, projT, 1024, 1024, 1024, 0, 0, 1024);
    for (int c = 0; c < NC; c++) {
        size_t roff = (size_t)c * R;
        rmsnorm_kernel<<<(int)R, 256, 0, stream>>>(x + roff * E_DIM, g1, xn);
        gemm256<0><<<dim3(12, gy256), 512, 0, stream>>>(xn, 1024, qkvT, 1024,
                b_qkv, nullptr, qkv, (int)R, 3072, 1024, 3072, 0);
        rope_kernel<<<(int)(2 * R), 256, 0, stream>>>(qkv);
        vtrans_kernel<<<dim3(17, 16, CB), 256, 0, stream>>>(qkv, Vt);
        attn_kernel<<<dim3(17, 16, CB), 256, 0, stream>>>(qkv, Vt, attnb + roff * E_DIM);
    }
    gemm256<1><<<dim3(4, (MROWS + 255) / 256), 512, 0, stream>>>(attnb, 1024,
            projT, 1024, b_proj, x, out, MROWS, 1024, 1024, 1024, 0);

    // ---- MLP phase ----
    convt_kernel<<<dim3(172, 32), 256, 0, stream>>>(fc1_w, fc1T, 1024, FC1_N, 1024,
            HID_DIM, XG_OFF, 5460);
    convt_kernel<<<dim3(32, 86), 256, 0, stream>>>(fc2_w, fc2T, HID_DIM, 1024, KP_FC2,
            0, 0, 1024);
    bias_perm_kernel<<<22, 256, 0, stream>>>(fc1_b, fc1bp);
    for (int c = 0; c < NC; c++) {
        size_t roff = (size_t)c * R;
        float* outc = out + roff * E_DIM;
        rmsnorm_kernel<<<(int)R, 256, 0, stream>>>(outc, g2, xn);
        gemm256<0><<<dim3(22, gy256), 512, 0, stream>>>(xn, 1024, fc1T, 1024,
                fc1bp, nullptr, hbuf, (int)R, FC1_N, 1024, HB_LD, 0);
        conv_gelu_kernel<<<(int)R, 256, 0, stream>>>(hbuf, dw_w, dw_b);
        // K-split x2: outc already holds the residual (from proj); both splits atomicAdd,
        // split 0 contributes the bias. 2752 = 1408 + 1344, both %64 == 0.
        gemm256<2><<<dim3(4, gy256, 2), 512, 0, stream>>>(hbuf, HB_LD, fc2T, KP_FC2,
                fc2_b, nullptr, outc, (int)R, 1024, KP_FC2, 1024, 1408);
    }
}

// Round 7
// 783.056 us; speedup vs baseline: 1.3896x; 1.0395x over previous
//
#include <hip/hip_runtime.h>
#include <hip/hip_bf16.h>
#include <math.h>

#define E_DIM 1024
#define NHEAD 16
#define HID_DIM 2730
#define KP_FC2 2752            // fc2 K padded (zero weight rows) -> mult of 64
#define HB_LD 5504             // hbuf row stride (16B-aligned)
#define XG_OFF 2752            // xg half starts here (16B-aligned); cols [2730,2752) are 0
#define FC1_N 5482             // 2730 vg + 22 zero + 2730 xg
#define B_DIM 8
#define S_DIM 1025
#define EPS_V 1e-6f
#define SCALE_V 0.125f
#define MROWS (B_DIM * S_DIM)   // 8200

typedef __attribute__((ext_vector_type(8))) short short8;
typedef __attribute__((ext_vector_type(4))) float f32x4;
typedef unsigned short us;

__device__ __forceinline__ float b2f(us u) {
    union { unsigned int i; float f; } x; x.i = ((unsigned int)u) << 16; return x.f;
}
__device__ __forceinline__ us f2b(float f) {
    __hip_bfloat16 h = __float2bfloat16(f);
    return *reinterpret_cast<us*>(&h);
}

__device__ __forceinline__ void stage16(const void* g, void* l) {
    __builtin_amdgcn_global_load_lds(
        (const __attribute__((address_space(1))) unsigned int*)g,
        (__attribute__((address_space(3))) unsigned int*)l,
        16, 0, 0);
}

// u16 index of the 8-element group at (row, c8) in a XOR-swizzled [R][64] bf16 tile
__device__ __forceinline__ int sl(int row, int c8) {
    return (row * 8 + (c8 ^ (row & 7))) * 8;
}

#define MFMA16(a, b, c) __builtin_amdgcn_mfma_f32_16x16x32_bf16(a, b, c, 0, 0, 0)

// ---------------- RMSNorm (fp32 in -> bf16 out) ----------------
__global__ __launch_bounds__(256) void rmsnorm_kernel(const float* __restrict__ x,
        const float* __restrict__ g, us* __restrict__ out) {
    int row = blockIdx.x;
    const float4* xr = (const float4*)(x + (size_t)row * E_DIM);
    float4 v = xr[threadIdx.x];
    float ss = v.x*v.x + v.y*v.y + v.z*v.z + v.w*v.w;
    #pragma unroll
    for (int off = 32; off > 0; off >>= 1) ss += __shfl_down(ss, off, 64);
    __shared__ float wsum[4];
    int lane = threadIdx.x & 63, w = threadIdx.x >> 6;
    if (lane == 0) wsum[w] = ss;
    __syncthreads();
    float tot = wsum[0] + wsum[1] + wsum[2] + wsum[3];
    float inv = rsqrtf(tot * (1.0f / E_DIM) + EPS_V);
    float4 gv = ((const float4*)g)[threadIdx.x];
    ushort4 o;
    o.x = f2b(v.x * inv * gv.x); o.y = f2b(v.y * inv * gv.y);
    o.z = f2b(v.z * inv * gv.z); o.w = f2b(v.w * inv * gv.w);
    ((ushort4*)(out + (size_t)row * E_DIM))[threadIdx.x] = o;
}

// ---------------- RMSNorm with partial-sum fold-in: x += p; then norm(x) -> out ----------
__global__ __launch_bounds__(256) void rmsnorm_add_kernel(float* __restrict__ x,
        const float* __restrict__ p, const float* __restrict__ g, us* __restrict__ out) {
    int row = blockIdx.x;
    float4* xr = (float4*)(x + (size_t)row * E_DIM);
    const float4* pr = (const float4*)(p + (size_t)row * E_DIM);
    float4 v = xr[threadIdx.x];
    float4 pv = pr[threadIdx.x];
    v.x += pv.x; v.y += pv.y; v.z += pv.z; v.w += pv.w;
    xr[threadIdx.x] = v;                       // write back completed residual
    float ss = v.x*v.x + v.y*v.y + v.z*v.z + v.w*v.w;
    #pragma unroll
    for (int off = 32; off > 0; off >>= 1) ss += __shfl_down(ss, off, 64);
    __shared__ float wsum[4];
    int lane = threadIdx.x & 63, w = threadIdx.x >> 6;
    if (lane == 0) wsum[w] = ss;
    __syncthreads();
    float tot = wsum[0] + wsum[1] + wsum[2] + wsum[3];
    float inv = rsqrtf(tot * (1.0f / E_DIM) + EPS_V);
    float4 gv = ((const float4*)g)[threadIdx.x];
    ushort4 o;
    o.x = f2b(v.x * inv * gv.x); o.y = f2b(v.y * inv * gv.y);
    o.z = f2b(v.z * inv * gv.z); o.w = f2b(v.w * inv * gv.w);
    ((ushort4*)(out + (size_t)row * E_DIM))[threadIdx.x] = o;
}

// ---------------- dst += p (float4 grid-stride) ----------------
__global__ __launch_bounds__(256) void addreduce_kernel(float* __restrict__ dst,
        const float* __restrict__ p, int n4) {
    int stride = gridDim.x * 256;
    for (int i = blockIdx.x * 256 + threadIdx.x; i < n4; i += stride) {
        float4 a = ((const float4*)p)[i];
        float4 d = ((float4*)dst)[i];
        d.x += a.x; d.y += a.y; d.z += a.z; d.w += a.w;
        ((float4*)dst)[i] = d;
    }
}

// ---------------- weight convert+transpose: W[K][Wld] f32 -> WT[n][k] bf16 ----------------
// N = output row count; Wld = SOURCE row stride (true width of W).
// swap_half != 0: row n sources col n+swap_half (n<swap_half), col n-xg_off (n>=xg_off), else 0.
__global__ __launch_bounds__(256) void convt_kernel(const float* __restrict__ W,
        us* __restrict__ WT, int K, int N, int KPad, int swap_half, int xg_off, int Wld) {
    __shared__ float T[32][33];
    int n0 = blockIdx.x * 32, k0 = blockIdx.y * 32;
    int c = threadIdx.x & 31, r4 = (threadIdx.x >> 5) << 2;
    #pragma unroll
    for (int i = 0; i < 4; i++) {
        int k = k0 + r4 + i, n = n0 + c;
        float v = 0.0f;
        if (k < K && n < N) {
            int src = n;
            int ok = 1;
            if (swap_half) {
                if (n < swap_half) src = n + swap_half;
                else if (xg_off) { if (n >= xg_off) src = n - xg_off; else ok = 0; }
                else src = n - swap_half;
            }
            if (ok) v = W[(size_t)k * Wld + src];
        }
        T[c][r4 + i] = v;
    }
    __syncthreads();
    #pragma unroll
    for (int i = 0; i < 4; i++) {
        int n = n0 + r4 + i, k = k0 + c;
        if (n < N && k < KPad) WT[(size_t)n * KPad + k] = f2b(T[r4 + i][c]);
    }
}

// ---------------- fc1 bias permute (vg | 22 zeros | xg) ----------------
__global__ __launch_bounds__(256) void bias_perm_kernel(const float* __restrict__ b,
        float* __restrict__ bp) {
    int r = blockIdx.x * 256 + threadIdx.x;
    if (r < FC1_N)
        bp[r] = (r < HID_DIM) ? b[r + HID_DIM] : ((r < XG_OFF) ? 0.0f : b[r - XG_OFF]);
}

// ---------------- 256x256 8-wave MFMA GEMM, balanced 4-phase counted-vmcnt ----------------
// MODE 0: bf16 out = acc+bias; MODE 1: f32 out = acc+bias+Rres;
// MODE 2: K-split over blockIdx.z, NO atomics: z==0 -> f32 out = acc+bias+Rres (plain),
//         z==1 -> Pbuf = acc (plain). Combined later by rmsnorm_add / addreduce.
template<int MODE>
__global__ __launch_bounds__(512, 2) void gemm256(const us* __restrict__ A, int lda,
        const us* __restrict__ Bt, int ldb, const float* __restrict__ bias,
        const float* __restrict__ Rres, void* __restrict__ Cv,
        int M, int N, int K, int ldc, int Ksplit, float* __restrict__ Pbuf) {
    __shared__ __align__(16) us lds[2][4][8192];
    us* const L = &lds[0][0][0];
    const int tid = threadIdx.x;
    const int lane = tid & 63;
    const int w = tid >> 6;
    const int wm = w >> 2, wn = w & 3;           // 2 x 4 wave grid, wave tile 128x64
    const int l15 = lane & 15, quad = lane >> 4;

    // T1: XCD-aware bijective block swizzle (m204)
    const int nwg = gridDim.x * gridDim.y;
    const int orig = blockIdx.y * gridDim.x + blockIdx.x;
    const int q8 = nwg >> 3, r8 = nwg & 7;
    const int xcd = orig & 7, oi = orig >> 3;
    const int wgid = (xcd < r8 ? xcd * (q8 + 1) : r8 * (q8 + 1) + (xcd - r8) * q8) + oi;
    const int m0 = (wgid / gridDim.x) * 256, n0 = (wgid % gridDim.x) * 256;

    const int kz = (MODE == 2) ? (int)blockIdx.z : 0;
    const int kofs = kz * Ksplit;
    const int Keff = (MODE == 2) ? (kz ? K - Ksplit : Ksplit) : K;

    const int r0 = tid >> 3;
    const int c80 = (tid & 7) ^ (r0 & 7);
    const us* const pA = A + (size_t)(m0 + r0) * lda + kofs + c80 * 8;
    const us* const pB = Bt + (size_t)(n0 + r0) * ldb + kofs + c80 * 8;
    const size_t a64 = (size_t)64 * lda, b64 = (size_t)64 * ldb;
    us* const dst = L + tid * 8;

#define STG_A(b, h, kt) do { \
    const us* s_ = pA + (size_t)(h) * 2 * a64 + (size_t)(kt) * 64; \
    stage16(s_,       dst + ((b) * 4 + (h)) * 8192); \
    stage16(s_ + a64, dst + ((b) * 4 + (h)) * 8192 + 4096); \
} while (0)
#define STG_B(b, h, kt) do { \
    const us* s_ = pB + (size_t)(h) * 2 * b64 + (size_t)(kt) * 64; \
    stage16(s_,       dst + ((b) * 4 + 2 + (h)) * 8192); \
    stage16(s_ + b64, dst + ((b) * 4 + 2 + (h)) * 8192 + 4096); \
} while (0)

    f32x4 acc[8][4];
    #pragma unroll
    for (int m = 0; m < 8; m++)
        #pragma unroll
        for (int n = 0; n < 4; n++) acc[m][n] = (f32x4){0.f, 0.f, 0.f, 0.f};

    const int nk = Keff >> 6;
    const int brow = (wn & 1) * 64;

    // prologue: tile0 + tile1 staged; drain tile0; barrier publishes
    STG_A(0, 0, 0); STG_A(0, 1, 0);
    STG_B(0, 0, 0); STG_B(0, 1, 0);
    if (nk > 1) {
        STG_B(1, 0, 1); STG_B(1, 1, 1);
        STG_A(1, 0, 1); STG_A(1, 1, 1);
        asm volatile("s_waitcnt vmcnt(8)" ::: "memory");
    } else {
        asm volatile("s_waitcnt vmcnt(0)" ::: "memory");
    }
    __builtin_amdgcn_s_barrier();
    __builtin_amdgcn_sched_barrier(0);

    short8 bf01[2][2];
    {
        const us* bB0 = L + (2 + (wn >> 1)) * 8192;
        #pragma unroll
        for (int n = 0; n < 2; n++) {
            bf01[n][0] = *(const short8*)(bB0 + sl(brow + n * 16 + l15, quad));
            bf01[n][1] = *(const short8*)(bB0 + sl(brow + n * 16 + l15, 4 + quad));
        }
    }

    for (int t = 0; t < nk; t++) {
        const int c = t & 1, cn = c ^ 1;
        const us* aB = L + (c * 4 + wm) * 8192;
        const us* bB = L + (c * 4 + 2 + (wn >> 1)) * 8192;
        const us* bBn = L + (cn * 4 + 2 + (wn >> 1)) * 8192;
        short8 bf2[2][2];
        #pragma unroll
        for (int n = 0; n < 2; n++) {
            bf2[n][0] = *(const short8*)(bB + sl(brow + (n + 2) * 16 + l15, quad));
            bf2[n][1] = *(const short8*)(bB + sl(brow + (n + 2) * 16 + l15, 4 + quad));
        }
        #pragma unroll
        for (int p = 0; p < 4; p++) {
            const int mp = 2 * p;
            short8 a00 = *(const short8*)(aB + sl(mp * 16 + l15, quad));
            short8 a01 = *(const short8*)(aB + sl(mp * 16 + l15, 4 + quad));
            short8 a10 = *(const short8*)(aB + sl(mp * 16 + 16 + l15, quad));
            short8 a11 = *(const short8*)(aB + sl(mp * 16 + 16 + l15, 4 + quad));
            if (p == 1) { if (t + 2 < nk) STG_B(c, 0, t + 2); }
            else if (p == 2) { if (t + 2 < nk) STG_B(c, 1, t + 2); }
            else if (p == 3) {
                // counted drain of A(t+1)+B(t+1) BEFORE the barrier -> barrier publishes
                if (t + 2 < nk)      { asm volatile("s_waitcnt vmcnt(4)" ::: "memory"); }
                else if (t + 1 < nk) { asm volatile("s_waitcnt vmcnt(0)" ::: "memory"); }
            }
            __builtin_amdgcn_s_barrier();
            if (p == 3) __builtin_amdgcn_sched_barrier(0);   // pin early-reads below barrier
            __builtin_amdgcn_s_setprio(1);
            #pragma unroll
            for (int n = 0; n < 4; n++) {
                const short8 b0 = (n < 2) ? bf01[n][0] : bf2[n - 2][0];
                const short8 b1 = (n < 2) ? bf01[n][1] : bf2[n - 2][1];
                acc[mp][n]     = MFMA16(a00, b0, acc[mp][n]);
                acc[mp][n]     = MFMA16(a01, b1, acc[mp][n]);
                acc[mp + 1][n] = MFMA16(a10, b0, acc[mp + 1][n]);
                acc[mp + 1][n] = MFMA16(a11, b1, acc[mp + 1][n]);
            }
            __builtin_amdgcn_s_setprio(0);
            if (p == 3) {
                if (t + 2 < nk) { STG_A(c, 0, t + 2); STG_A(c, 1, t + 2); }
                if (t + 1 < nk) {   // early-read next tile's B n=0,1 (published at barrier above)
                    #pragma unroll
                    for (int n = 0; n < 2; n++) {
                        bf01[n][0] = *(const short8*)(bBn + sl(brow + n * 16 + l15, quad));
                        bf01[n][1] = *(const short8*)(bBn + sl(brow + n * 16 + l15, 4 + quad));
                    }
                }
            }
            __builtin_amdgcn_s_barrier();
            if (p == 3) __builtin_amdgcn_sched_barrier(0);   // no next-iter reads above this
        }
    }

    // epilogue
    #pragma unroll
    for (int m = 0; m < 8; m++) {
        int gm0 = m0 + wm * 128 + m * 16 + quad * 4;
        #pragma unroll
        for (int n = 0; n < 4; n++) {
            int gn = n0 + wn * 64 + n * 16 + l15;
            if (gn >= N) continue;
            float bs = (MODE == 2) ? (kz == 0 ? bias[gn] : 0.0f) : bias[gn];
            #pragma unroll
            for (int r = 0; r < 4; r++) {
                int gm = gm0 + r;
                if (gm >= M) continue;
                float v = acc[m][n][r] + bs;
                if (MODE == 0) {
                    ((us*)Cv)[(size_t)gm * ldc + gn] = f2b(v);
                } else if (MODE == 1) {
                    ((float*)Cv)[(size_t)gm * ldc + gn] = v + Rres[(size_t)gm * ldc + gn];
                } else {
                    if (kz == 0)
                        ((float*)Cv)[(size_t)gm * ldc + gn] = v + Rres[(size_t)gm * ldc + gn];
                    else
                        Pbuf[(size_t)gm * ldc + gn] = v;
                }
            }
        }
    }
#undef STG_A
#undef STG_B
}

// ---------------- RoPE (in-place) + q*SCALE ----------------
__global__ __launch_bounds__(256) void rope_kernel(us* __restrict__ qkv) {
    int idx = blockIdx.x * 256 + threadIdx.x;
    int i = idx & 31;
    int h = (idx >> 5) & (NHEAD - 1);
    int rc = idx >> 9;
    int s = rc % S_DIM;
    us* q = qkv + (size_t)rc * 3072 + h * 64;
    us* k = q + 1024;
    if (s == 0) {
        q[i] = f2b(b2f(q[i]) * SCALE_V);
        q[i + 32] = f2b(b2f(q[i + 32]) * SCALE_V);
        return;
    }
    float pos = (float)(s - 1);
    float invf = expf((float)i * (-9.210340371976184f / 32.0f));
    float f = pos * invf;
    float c = cosf(f), sn = sinf(f);
    float q1 = b2f(q[i]), q2 = b2f(q[i + 32]);
    q[i]      = f2b((q1 * c - q2 * sn) * SCALE_V);
    q[i + 32] = f2b((q2 * c + q1 * sn) * SCALE_V);
    float k1 = b2f(k[i]), k2 = b2f(k[i + 32]);
    k[i]      = f2b(k1 * c - k2 * sn);
    k[i + 32] = f2b(k2 * c + k1 * sn);
}

// ---------------- V transpose ----------------
__global__ __launch_bounds__(256) void vtrans_kernel(const us* __restrict__ qkv,
        us* __restrict__ Vt) {
    __shared__ us T[64][65];
    int st = blockIdx.x, h = blockIdx.y, bc = blockIdx.z;
    int tid = threadIdx.x;
    int r = tid & 63, cb = (tid >> 6) * 16;
    const us* src = qkv + (size_t)(bc * S_DIM + st * 64 + r) * 3072 + 2048 + h * 64 + cb;
    #pragma unroll
    for (int i = 0; i < 4; i++) {
        ushort4 v = *(const ushort4*)(src + i * 4);
        T[cb + i*4 + 0][r] = v.x; T[cb + i*4 + 1][r] = v.y;
        T[cb + i*4 + 2][r] = v.z; T[cb + i*4 + 3][r] = v.w;
    }
    __syncthreads();
    int d = tid >> 2, sc = (tid & 3) * 16;
    us* dstp = Vt + ((size_t)((bc * 16 + h) * 64 + d)) * 1088 + st * 64 + sc;
    #pragma unroll
    for (int g = 0; g < 4; g++) {
        ushort4 o;
        int i0 = sc + g * 4;
        o.x = (st*64 + i0 + 0 < S_DIM) ? T[d][i0 + 0] : 0;
        o.y = (st*64 + i0 + 1 < S_DIM) ? T[d][i0 + 1] : 0;
        o.z = (st*64 + i0 + 2 < S_DIM) ? T[d][i0 + 2] : 0;
        o.w = (st*64 + i0 + 3 < S_DIM) ? T[d][i0 + 3] : 0;
        *(ushort4*)(dstp + g * 4) = o;
    }
}

// ---------------- MFMA flash attention (round-2 proven) ----------------
__global__ __launch_bounds__(256) void attn_kernel(const us* __restrict__ qkv,
        const us* __restrict__ Vt, us* __restrict__ attnb) {
    __shared__ __align__(16) us Kb[2][4096];
    __shared__ __align__(16) us Vb[2][4096];
    __shared__ __align__(16) us Ps[4096];
    int qt = blockIdx.x, h = blockIdx.y, bc = blockIdx.z;
    int tid = threadIdx.x;
    int lane = tid & 63, w = tid >> 6;
    int l15 = lane & 15, quad = lane >> 4;

    const us* qrow = qkv + (size_t)(bc * S_DIM + qt * 64 + 16 * w + l15) * 3072 + h * 64;
    short8 qa0 = *(const short8*)(qrow + quad * 8);
    short8 qa1 = *(const short8*)(qrow + 32 + quad * 8);

    const us* kg = qkv + (size_t)(bc * S_DIM) * 3072 + 1024 + h * 64;
    const us* vgp = Vt + (size_t)((bc * 16 + h) * 64) * 1088;

    int s0 = tid, s1 = 256 + tid;
    int row0 = s0 >> 3, c8_0 = (s0 & 7) ^ (row0 & 7);
    int row1 = s1 >> 3, c8_1 = (s1 & 7) ^ (row1 & 7);

    f32x4 acc_o[4];
    float mr[4], lr[4];
    #pragma unroll
    for (int r = 0; r < 4; r++) { mr[r] = -1e30f; lr[r] = 0.f; }
    #pragma unroll
    for (int j = 0; j < 4; j++) acc_o[j] = (f32x4){0.f, 0.f, 0.f, 0.f};

    stage16(kg + (size_t)row0 * 3072 + c8_0 * 8, Kb[0] + s0 * 8);
    stage16(vgp + (size_t)row0 * 1088 + c8_0 * 8, Vb[0] + s0 * 8);
    stage16(kg + (size_t)row1 * 3072 + c8_1 * 8, Kb[0] + s1 * 8);
    stage16(vgp + (size_t)row1 * 1088 + c8_1 * 8, Vb[0] + s1 * 8);
    __syncthreads();

    for (int kt = 0; kt < 17; kt++) {
        int cur = kt & 1, nxt = cur ^ 1;
        if (kt + 1 < 17) {
            stage16(kg + (size_t)((kt + 1) * 64 + row0) * 3072 + c8_0 * 8, Kb[nxt] + s0 * 8);
            stage16(vgp + (size_t)row0 * 1088 + (kt + 1) * 64 + c8_0 * 8, Vb[nxt] + s0 * 8);
            stage16(kg + (size_t)((kt + 1) * 64 + row1) * 3072 + c8_1 * 8, Kb[nxt] + s1 * 8);
            stage16(vgp + (size_t)row1 * 1088 + (kt + 1) * 64 + c8_1 * 8, Vb[nxt] + s1 * 8);
        }

        f32x4 accS[4];
        #pragma unroll
        for (int j = 0; j < 4; j++) accS[j] = (f32x4){0.f, 0.f, 0.f, 0.f};
        __builtin_amdgcn_s_setprio(1);
        #pragma unroll
        for (int j = 0; j < 4; j++) {
            short8 kb0 = *(const short8*)(Kb[cur] + sl(16 * j + l15, quad));
            short8 kb1 = *(const short8*)(Kb[cur] + sl(16 * j + l15, 4 + quad));
            accS[j] = MFMA16(qa0, kb0, accS[j]);
            accS[j] = MFMA16(qa1, kb1, accS[j]);
        }
        __builtin_amdgcn_s_setprio(0);

        #pragma unroll
        for (int j = 0; j < 4; j++) {
            if (kt * 64 + 16 * j + l15 >= S_DIM) {
                #pragma unroll
                for (int r = 0; r < 4; r++) accS[j][r] = -1e30f;
            }
        }

        float tm[4];
        #pragma unroll
        for (int r = 0; r < 4; r++) {
            float t = fmaxf(fmaxf(accS[0][r], accS[1][r]), fmaxf(accS[2][r], accS[3][r]));
            #pragma unroll
            for (int off = 1; off < 16; off <<= 1)
                t = fmaxf(t, __shfl_xor(t, off, 64));
            tm[r] = t;
        }
        int need = (tm[0] > mr[0] + 8.f) || (tm[1] > mr[1] + 8.f) ||
                   (tm[2] > mr[2] + 8.f) || (tm[3] > mr[3] + 8.f);
        if (__any(need)) {
            #pragma unroll
            for (int r = 0; r < 4; r++) {
                float mnew = fmaxf(mr[r], tm[r]);
                float al = __expf(mr[r] - mnew);
                mr[r] = mnew;
                lr[r] *= al;
                #pragma unroll
                for (int j = 0; j < 4; j++) acc_o[j][r] *= al;
            }
        }
        float pr[4][4];
        #pragma unroll
        for (int r = 0; r < 4; r++) {
            float rs = 0.f;
            #pragma unroll
            for (int j = 0; j < 4; j++) {
                float p = __expf(accS[j][r] - mr[r]);
                pr[j][r] = p;
                rs += p;
            }
            lr[r] += rs;
        }
        #pragma unroll
        for (int j = 0; j < 4; j++) {
            #pragma unroll
            for (int r = 0; r < 4; r++) {
                int prow = quad * 4 + r;
                int idx = sl(16 * w + prow, 2 * j + (l15 >> 3)) + (l15 & 7);
                Ps[idx] = f2b(pr[j][r]);
            }
        }
        short8 pa0 = *(const short8*)(Ps + sl(16 * w + l15, quad));
        short8 pa1 = *(const short8*)(Ps + sl(16 * w + l15, 4 + quad));
        __builtin_amdgcn_s_setprio(1);
        #pragma unroll
        for (int j = 0; j < 4; j++) {
            short8 vb0 = *(const short8*)(Vb[cur] + sl(16 * j + l15, quad));
            short8 vb1 = *(const short8*)(Vb[cur] + sl(16 * j + l15, 4 + quad));
            acc_o[j] = MFMA16(pa0, vb0, acc_o[j]);
            acc_o[j] = MFMA16(pa1, vb1, acc_o[j]);
        }
        __builtin_amdgcn_s_setprio(0);
        __syncthreads();
    }

    #pragma unroll
    for (int r = 0; r < 4; r++) {
        #pragma unroll
        for (int off = 1; off < 16; off <<= 1)
            lr[r] += __shfl_xor(lr[r], off, 64);
    }
    #pragma unroll
    for (int r = 0; r < 4; r++) {
        int s = qt * 64 + 16 * w + quad * 4 + r;
        if (s >= S_DIM) continue;
        float invl = 1.0f / lr[r];
        #pragma unroll
        for (int j = 0; j < 4; j++)
            attnb[(size_t)(bc * S_DIM + s) * E_DIM + h * 64 + 16 * j + l15] =
                f2b(acc_o[j][r] * invl);
    }
}

// ---------------- depthwise conv + GELU + gate, vectorized (xg at XG_OFF, 16B-aligned) ----
__global__ __launch_bounds__(256) void conv_gelu_kernel(us* __restrict__ hb,
        const float* __restrict__ dw_w, const float* __restrict__ dw_b) {
    int p = blockIdx.x % S_DIM;
    size_t row = blockIdx.x;
    size_t brow = row - p;
    int pp = p - 1;
    int gy = pp >> 5, gx = pp & 31;
    for (int g = threadIdx.x; g < 342; g += 256) {
        int c0 = g * 8;
        if (c0 + 8 <= HID_DIM) {
            float val[8];
            if (p == 0) {
                short8 xv = *(const short8*)(hb + row * HB_LD + XG_OFF + c0);
                #pragma unroll
                for (int e = 0; e < 8; e++) val[e] = b2f((us)xv[e]);
            } else {
                #pragma unroll
                for (int e = 0; e < 8; e++) val[e] = dw_b[c0 + e];
                #pragma unroll
                for (int dy = 0; dy < 3; dy++) {
                    int ny = gy + dy - 1;
                    if (ny < 0 || ny >= 32) continue;
                    #pragma unroll
                    for (int dx = 0; dx < 3; dx++) {
                        int nx = gx + dx - 1;
                        if (nx < 0 || nx >= 32) continue;
                        short8 xv = *(const short8*)(hb +
                                (brow + 1 + ny * 32 + nx) * HB_LD + XG_OFF + c0);
                        const float* wp = dw_w + (dy * 3 + dx) * HID_DIM + c0;
                        float2 w0 = *(const float2*)(wp);
                        float2 w1 = *(const float2*)(wp + 2);
                        float2 w2 = *(const float2*)(wp + 4);
                        float2 w3 = *(const float2*)(wp + 6);
                        val[0] = fmaf(b2f((us)xv[0]), w0.x, val[0]);
                        val[1] = fmaf(b2f((us)xv[1]), w0.y, val[1]);
                        val[2] = fmaf(b2f((us)xv[2]), w1.x, val[2]);
                        val[3] = fmaf(b2f((us)xv[3]), w1.y, val[3]);
                        val[4] = fmaf(b2f((us)xv[4]), w2.x, val[4]);
                        val[5] = fmaf(b2f((us)xv[5]), w2.y, val[5]);
                        val[6] = fmaf(b2f((us)xv[6]), w3.x, val[6]);
                        val[7] = fmaf(b2f((us)xv[7]), w3.y, val[7]);
                    }
                }
            }
            short8 gv = *(const short8*)(hb + row * HB_LD + c0);
            short8 o;
            #pragma unroll
            for (int e = 0; e < 8; e++) {
                float ge = 0.5f * val[e] * (1.0f + erff(val[e] * 0.70710678118654752f));
                o[e] = (short)f2b(ge * b2f((us)gv[e]));
            }
            *(short8*)(hb + row * HB_LD + c0) = o;
        } else {
            for (int c = c0; c < HID_DIM; c++) {
                float val;
                if (p == 0) {
                    val = b2f(hb[row * HB_LD + XG_OFF + c]);
                } else {
                    float a = dw_b[c];
                    #pragma unroll
                    for (int dy = 0; dy < 3; dy++) {
                        int ny = gy + dy - 1;
                        if (ny < 0 || ny >= 32) continue;
                        #pragma unroll
                        for (int dx = 0; dx < 3; dx++) {
                            int nx = gx + dx - 1;
                            if (nx < 0 || nx >= 32) continue;
                            a = fmaf(b2f(hb[(brow + 1 + ny * 32 + nx) * HB_LD + XG_OFF + c]),
                                     dw_w[(dy * 3 + dx) * HID_DIM + c], a);
                        }
                    }
                    val = a;
                }
                float ge = 0.5f * val * (1.0f + erff(val * 0.70710678118654752f));
                hb[row * HB_LD + c] = f2b(ge * b2f(hb[row * HB_LD + c]));
            }
        }
    }
}

// ---------------- launch ----------------
static size_t ws_need(int cb) {
    size_t R = (size_t)cb * 1025, Rp = ((R + 127) / 128) * 128;
    size_t end1 = Rp*1024*2 + Rp*3072*2 + (size_t)cb*16*64*1088*2
                + 8320ull*1024*2 + 3072ull*1024*2 + 1024ull*1024*2;
    size_t end2 = Rp*1024*2 + Rp*HB_LD*2 + 5504ull*1024*2 + 1024ull*KP_FC2*2 + 5504*4;
    return end1 > end2 ? end1 : end2;
}

extern "C" void kernel_launch(void* const* d_in, const int* in_sizes, int n_in,
                              void* d_out, int out_size, void* d_ws, size_t ws_size,
                              hipStream_t stream) {
    const float* x      = (const float*)d_in[0];
    const float* g1     = (const float*)d_in[1];
    const float* w_qkv  = (const float*)d_in[2];
    const float* b_qkv  = (const float*)d_in[3];
    const float* w_proj = (const float*)d_in[4];
    const float* b_proj = (const float*)d_in[5];
    const float* g2     = (const float*)d_in[6];
    const float* fc1_w  = (const float*)d_in[7];
    const float* fc1_b  = (const float*)d_in[8];
    const float* dw_w   = (const float*)d_in[9];
    const float* dw_b   = (const float*)d_in[10];
    const float* fc2_w  = (const float*)d_in[11];
    const float* fc2_b  = (const float*)d_in[12];
    float* out = (float*)d_out;
    char* base = (char*)d_ws;

    int CB = 2;
    if (ws_size >= ws_need(8)) CB = 8;
    else if (ws_size >= ws_need(4)) CB = 4;
    int NC = B_DIM / CB;
    size_t R = (size_t)CB * 1025, Rp = ((R + 127) / 128) * 128;
    int gy256 = (int)((R + 255) / 256);
    int gyM = (MROWS + 255) / 256;

    // K-split partial buffer (ws-gated; falls back to unsplit MODE 1 if it doesn't fit)
    size_t pOff = ((ws_need(CB) + 255) / 256) * 256;
    size_t pBytes = (size_t)MROWS * E_DIM * 4;
    int use_split = (ws_size >= pOff + pBytes);
    float* P1 = (float*)(base + pOff);

    // phase-1 layout
    us* xn    = (us*)base;                       // Rp x 1024
    size_t o  = Rp * 1024 * 2;
    us* qkv   = (us*)(base + o);                 // Rp x 3072 (phase1)
    us* hbuf  = (us*)(base + o);                 // Rp x HB_LD (phase2 overlay)
    size_t o2 = o + Rp * 3072 * 2;
    us* Vt    = (us*)(base + o2);                // CB x 16 x 64 x 1088
    size_t o3 = o2 + (size_t)CB * 16 * 64 * 1088 * 2;
    us* attnb = (us*)(base + o3);                // 8320 x 1024
    size_t o4 = o3 + 8320ull * 1024 * 2;
    us* qkvT  = (us*)(base + o4);                // 3072 x 1024
    size_t o5 = o4 + 3072ull * 1024 * 2;
    us* projT = (us*)(base + o5);                // 1024 x 1024
    // phase-2 layout (overlays qkv/Vt/attnb/qkvT/projT)
    size_t p2 = o + Rp * HB_LD * 2;
    us* fc1T  = (us*)(base + p2);                // 5504 x 1024
    size_t p3 = p2 + 5504ull * 1024 * 2;
    us* fc2T  = (us*)(base + p3);                // 1024 x KP_FC2
    float* fc1bp = (float*)(base + p3 + 1024ull * KP_FC2 * 2);   // 5504 f32

    // ---- attention phase ----
    convt_kernel<<<dim3(96, 32), 256, 0, stream>>>(w_qkv, qkvT, 1024, 3072, 1024, 0, 0, 3072);
    convt_kernel<<<dim3(32, 32), 256, 0, stream>>>(w_proj, projT, 1024, 1024, 1024, 0, 0, 1024);
    for (int c = 0; c < NC; c++) {
        size_t roff = (size_t)c * R;
        rmsnorm_kernel<<<(int)R, 256, 0, stream>>>(x + roff * E_DIM, g1, xn);
        gemm256<0><<<dim3(12, gy256), 512, 0, stream>>>(xn, 1024, qkvT, 1024,
                b_qkv, nullptr, qkv, (int)R, 3072, 1024, 3072, 0, nullptr);
        rope_kernel<<<(int)(2 * R), 256, 0, stream>>>(qkv);
        vtrans_kernel<<<dim3(17, 16, CB), 256, 0, stream>>>(qkv, Vt);
        attn_kernel<<<dim3(17, 16, CB), 256, 0, stream>>>(qkv, Vt, attnb + roff * E_DIM);
    }
    // proj: K-split x2 (512+512) without atomics when ws allows; partial folded into rmsnorm
    if (use_split) {
        gemm256<2><<<dim3(4, gyM, 2), 512, 0, stream>>>(attnb, 1024, projT, 1024,
                b_proj, x, out, MROWS, 1024, 1024, 1024, 512, P1);
    } else {
        gemm256<1><<<dim3(4, gyM), 512, 0, stream>>>(attnb, 1024, projT, 1024,
                b_proj, x, out, MROWS, 1024, 1024, 1024, 0, nullptr);
    }

    // ---- MLP phase ----
    convt_kernel<<<dim3(172, 32), 256, 0, stream>>>(fc1_w, fc1T, 1024, FC1_N, 1024,
            HID_DIM, XG_OFF, 5460);
    convt_kernel<<<dim3(32, 86), 256, 0, stream>>>(fc2_w, fc2T, HID_DIM, 1024, KP_FC2,
            0, 0, 1024);
    bias_perm_kernel<<<22, 256, 0, stream>>>(fc1_b, fc1bp);
    for (int c = 0; c < NC; c++) {
        size_t roff = (size_t)c * R;
        float* outc = out + roff * E_DIM;
        if (use_split) {
            // fold proj's z=1 partial into the residual while computing the norm
            rmsnorm_add_kernel<<<(int)R, 256, 0, stream>>>(outc, P1 + roff * E_DIM, g2, xn);
        } else {
            rmsnorm_kernel<<<(int)R, 256, 0, stream>>>(outc, g2, xn);
        }
        gemm256<0><<<dim3(22, gy256), 512, 0, stream>>>(xn, 1024, fc1T, 1024,
                fc1bp, nullptr, hbuf, (int)R, FC1_N, 1024, HB_LD, 0, nullptr);
        conv_gelu_kernel<<<(int)R, 256, 0, stream>>>(hbuf, dw_w, dw_b);
        if (use_split) {
            // fc2: K-split x2 (1408+1344) without atomics; z=0 writes out+res, z=1 -> P1
            gemm256<2><<<dim3(4, gy256, 2), 512, 0, stream>>>(hbuf, HB_LD, fc2T, KP_FC2,
                    fc2_b, outc, outc, (int)R, 1024, KP_FC2, 1024, 1408, P1 + roff * E_DIM);
            addreduce_kernel<<<2048, 256, 0, stream>>>(outc, P1 + roff * E_DIM,
                    (int)(R * 256));
        } else {
            gemm256<1><<<dim3(4, gy256), 512, 0, stream>>>(hbuf, HB_LD, fc2T, KP_FC2,
                    fc2_b, outc, outc, (int)R, 1024, KP_FC2, 1024, 0, nullptr);
        }
    }
}